// Round 3
// baseline (409.935 us; speedup 1.0000x reference)
//
#include <hip/hip_runtime.h>
#include <hip/hip_cooperative_groups.h>

namespace cg = cooperative_groups;

#define NS 128
#define ND 128
#define NDK 32
#define NL 2

struct Params {
  const int* tok; const float* emb; const float* pos;
  const float* Wq; const float* bq; const float* Wk; const float* bk;
  const float* Wv; const float* bv; const float* Wo; const float* bo;
  const float* W1; const float* b1; const float* W2; const float* b2;
  const float* g1; const float* be1; const float* g2; const float* be2;
  const float* Wout; const float* bout;
  float* x; float* qb; float* kb; float* vb; float* ab; float* f1; float* out;
};

struct SmemMM { float Xs[32][33]; float Ws[32][33]; };
struct SmemAT { float Ks[128][33]; float Vs[128][33]; float Qs[32][33]; float Ps[32][129]; };
struct SmemLN { float As[4][132]; float Ws[64][133]; };
union SMem { SmemMM mm; SmemAT at; SmemLN ln; };

// f(v) = rint(m*8) * 2^(2e-3), v = m*2^e, 0.5<=|m|<1. Native frexp/ldexp VALU ops.
__device__ __forceinline__ float lmul_tf(float v) {
  int e; float m = frexpf(v, &e);
  return ldexpf(rintf(m * 8.0f), 2 * e - 3);
}

// One 32x32 output tile of out = f(X) @ f(W)^T + bias (optional relu).
__device__ __forceinline__ void mm_one_tile(
    const float* __restrict__ X, const float* __restrict__ W,
    const float* __restrict__ bias, float* __restrict__ out,
    int N, int K, int relu, int m0, int n0, SMem* sm)
{
  int t  = threadIdx.x;
  int tm = t >> 4, tn = t & 15;
  int lr = t >> 3, lc = (t & 7) * 4;
  float acc00 = 0.f, acc01 = 0.f, acc10 = 0.f, acc11 = 0.f;
  for (int k0 = 0; k0 < K; k0 += 32) {
    float4 xv = *(const float4*)(X + (size_t)(m0 + lr) * K + k0 + lc);
    sm->mm.Xs[lr][lc + 0] = lmul_tf(xv.x);
    sm->mm.Xs[lr][lc + 1] = lmul_tf(xv.y);
    sm->mm.Xs[lr][lc + 2] = lmul_tf(xv.z);
    sm->mm.Xs[lr][lc + 3] = lmul_tf(xv.w);
    float4 wv = *(const float4*)(W + (size_t)(n0 + lr) * K + k0 + lc);
    sm->mm.Ws[lr][lc + 0] = lmul_tf(wv.x);
    sm->mm.Ws[lr][lc + 1] = lmul_tf(wv.y);
    sm->mm.Ws[lr][lc + 2] = lmul_tf(wv.z);
    sm->mm.Ws[lr][lc + 3] = lmul_tf(wv.w);
    __syncthreads();
    #pragma unroll
    for (int kk = 0; kk < 32; ++kk) {
      float a0 = sm->mm.Xs[tm][kk],      a1 = sm->mm.Xs[tm + 16][kk];
      float b0 = sm->mm.Ws[tn][kk],      b1 = sm->mm.Ws[tn + 16][kk];
      acc00 += a0 * b0; acc01 += a0 * b1;
      acc10 += a1 * b0; acc11 += a1 * b1;
    }
    __syncthreads();
  }
  float bb0 = bias[n0 + tn], bb1 = bias[n0 + tn + 16];
  acc00 += bb0; acc01 += bb1; acc10 += bb0; acc11 += bb1;
  if (relu) {
    acc00 = fmaxf(acc00, 0.f); acc01 = fmaxf(acc01, 0.f);
    acc10 = fmaxf(acc10, 0.f); acc11 = fmaxf(acc11, 0.f);
  }
  out[(size_t)(m0 + tm) * N + n0 + tn]           = acc00;
  out[(size_t)(m0 + tm) * N + n0 + tn + 16]      = acc01;
  out[(size_t)(m0 + tm + 16) * N + n0 + tn]      = acc10;
  out[(size_t)(m0 + tm + 16) * N + n0 + tn + 16] = acc11;
}

// x = LN(x + f(A) @ f(W)^T + bias) * g + be.  64 blocks x 4 rows; wave = row.
__device__ __forceinline__ void mm_ln(
    const float* __restrict__ A, const float* __restrict__ W,
    const float* __restrict__ bias, const float* __restrict__ g,
    const float* __restrict__ be, float* __restrict__ x, int K, SMem* sm)
{
  int blk = blockIdx.x;
  if (blk >= 64) return;
  int t = threadIdx.x;
  int w = t >> 6, lane = t & 63;
  int m0 = blk * 4;
  float acc0 = 0.f, acc1 = 0.f;
  for (int k0 = 0; k0 < K; k0 += 128) {
    if (t < 128) {
      int r = t >> 5, c = (t & 31) * 4;
      float4 v = *(const float4*)(A + (size_t)(m0 + r) * K + k0 + c);
      sm->ln.As[r][c + 0] = lmul_tf(v.x);
      sm->ln.As[r][c + 1] = lmul_tf(v.y);
      sm->ln.As[r][c + 2] = lmul_tf(v.z);
      sm->ln.As[r][c + 3] = lmul_tf(v.w);
    }
    for (int half = 0; half < 2; ++half) {
      #pragma unroll
      for (int it = 0; it < 8; ++it) {
        int idx = t + it * 256;                 // 0..2047 float4s
        int n = idx >> 5, c4 = (idx & 31) * 4;
        float4 v = *(const float4*)(W + (size_t)(half * 64 + n) * K + k0 + c4);
        sm->ln.Ws[n][c4 + 0] = lmul_tf(v.x);
        sm->ln.Ws[n][c4 + 1] = lmul_tf(v.y);
        sm->ln.Ws[n][c4 + 2] = lmul_tf(v.z);
        sm->ln.Ws[n][c4 + 3] = lmul_tf(v.w);
      }
      __syncthreads();
      float accl = 0.f;
      #pragma unroll 8
      for (int kk = 0; kk < 128; kk += 4) {
        float4 a = *(const float4*)&sm->ln.As[w][kk];
        accl += a.x * sm->ln.Ws[lane][kk + 0]
              + a.y * sm->ln.Ws[lane][kk + 1]
              + a.z * sm->ln.Ws[lane][kk + 2]
              + a.w * sm->ln.Ws[lane][kk + 3];
      }
      if (half == 0) acc0 += accl; else acc1 += accl;
      __syncthreads();
    }
  }
  int row = m0 + w;
  float v0 = acc0 + bias[lane]      + x[row * 128 + lane];
  float v1 = acc1 + bias[lane + 64] + x[row * 128 + lane + 64];
  float s = v0 + v1, s2 = v0 * v0 + v1 * v1;
  #pragma unroll
  for (int off = 1; off < 64; off <<= 1) {
    s  += __shfl_xor(s,  off);
    s2 += __shfl_xor(s2, off);
  }
  float mu  = s * (1.0f / 128.0f);
  float var = s2 * (1.0f / 128.0f) - mu * mu;
  float rr = rsqrtf(var + 1e-5f);
  x[row * 128 + lane]      = (v0 - mu) * rr * g[lane]      + be[lane];
  x[row * 128 + lane + 64] = (v1 - mu) * rr * g[lane + 64] + be[lane + 64];
}

// 32 work items: (b,h) x 4 query tiles of 32.
__device__ __forceinline__ void attn_stage(
    const float* __restrict__ q, const float* __restrict__ k,
    const float* __restrict__ v, float* __restrict__ o, SMem* sm)
{
  int wrk = blockIdx.x;
  if (wrk >= 32) return;
  int t = threadIdx.x;
  int bh = wrk >> 2, qt = (wrk & 3) * 32;
  int b = bh >> 2, h = bh & 3;
  int base = b * NS * ND + h * NDK;
  for (int idx = t; idx < NS * NDK; idx += 256) {
    int s = idx >> 5, d = idx & 31;
    sm->at.Ks[s][d] = k[base + s * ND + d];
    sm->at.Vs[s][d] = v[base + s * ND + d];
  }
  for (int idx = t; idx < 32 * NDK; idx += 256) {
    int s = idx >> 5, d = idx & 31;
    sm->at.Qs[s][d] = q[base + (qt + s) * ND + d];
  }
  __syncthreads();
  int qi = t >> 3, kg = t & 7;
  const float scale = 0.17677669529663687f;  // 1/sqrt(32)
  for (int jj = 0; jj < 16; ++jj) {
    int j = kg * 16 + jj;
    float acc = 0.f;
    #pragma unroll
    for (int d = 0; d < NDK; ++d) acc += sm->at.Qs[qi][d] * sm->at.Ks[j][d];
    sm->at.Ps[qi][j] = acc * scale;
  }
  float mx = -1e30f;
  for (int jj = 0; jj < 16; ++jj) mx = fmaxf(mx, sm->at.Ps[qi][kg * 16 + jj]);
  #pragma unroll
  for (int off = 1; off < 8; off <<= 1) mx = fmaxf(mx, __shfl_xor(mx, off));
  float sum = 0.f;
  for (int jj = 0; jj < 16; ++jj) {
    int j = kg * 16 + jj;
    float e = expf(sm->at.Ps[qi][j] - mx);
    sm->at.Ps[qi][j] = e;
    sum += e;
  }
  #pragma unroll
  for (int off = 1; off < 8; off <<= 1) sum += __shfl_xor(sum, off);
  float inv = 1.f / sum;
  for (int jj = 0; jj < 16; ++jj) sm->at.Ps[qi][kg * 16 + jj] *= inv;
  __syncthreads();
  int d0 = (t & 7) * 4;
  float a0 = 0.f, a1 = 0.f, a2 = 0.f, a3 = 0.f;
  for (int j = 0; j < NS; ++j) {
    float p = sm->at.Ps[qi][j];
    a0 += p * sm->at.Vs[j][d0 + 0];
    a1 += p * sm->at.Vs[j][d0 + 1];
    a2 += p * sm->at.Vs[j][d0 + 2];
    a3 += p * sm->at.Vs[j][d0 + 3];
  }
  int orow = base + (qt + qi) * ND + d0;
  o[orow + 0] = a0; o[orow + 1] = a1; o[orow + 2] = a2; o[orow + 3] = a3;
}

__global__ __launch_bounds__(256) void k_model(Params p) {
  __shared__ SMem sm;
  cg::grid_group grid = cg::this_grid();
  int blk = blockIdx.x, t = threadIdx.x;

  // stage: embed (128*256 = 32768 = exactly one elem per thread)
  {
    int i = blk * 256 + t;
    int d = i & (ND - 1);
    int bs = i >> 7;
    int s = bs & (NS - 1);
    p.x[i] = p.emb[p.tok[bs] * ND + d] + p.pos[s * ND + d];
  }
  grid.sync();

  for (int l = 0; l < NL; ++l) {
    // QKV: 96 tiles (32 per projection)
    if (blk < 96) {
      int arr = blk >> 5, sub = blk & 31;
      int m0 = (sub >> 2) * 32, n0 = (sub & 3) * 32;
      const float* W = (arr == 0) ? p.Wq : (arr == 1) ? p.Wk : p.Wv;
      const float* bb = (arr == 0) ? p.bq : (arr == 1) ? p.bk : p.bv;
      float* dst = (arr == 0) ? p.qb : (arr == 1) ? p.kb : p.vb;
      mm_one_tile(p.x, W + l * 16384, bb + l * 128, dst, 128, 128, 0, m0, n0, &sm);
    }
    grid.sync();

    attn_stage(p.qb, p.kb, p.vb, p.ab, &sm);
    grid.sync();

    // x = LN(x + ab @ Wo^T + bo)
    mm_ln(p.ab, p.Wo + l * 16384, p.bo + l * 128,
          p.g1 + l * 128, p.be1 + l * 128, p.x, 128, &sm);
    grid.sync();

    // f1 = relu(x @ W1^T + b1): exactly 128 tiles
    mm_one_tile(p.x, p.W1 + l * 65536, p.b1 + l * 512, p.f1,
                512, 128, 1, (blk >> 4) * 32, (blk & 15) * 32, &sm);
    grid.sync();

    // x = LN(x + f1 @ W2^T + b2)
    mm_ln(p.f1, p.W2 + l * 65536, p.b2 + l * 128,
          p.g2 + l * 128, p.be2 + l * 128, p.x, 512, &sm);
    grid.sync();
  }

  // final: 256 tiles, 2 per block
  for (int tile = blk; tile < 256; tile += 128) {
    mm_one_tile(p.x, p.Wout, p.bout, p.out, 1024, 128, 0,
                (tile >> 5) * 32, (tile & 31) * 32, &sm);
  }
}

extern "C" void kernel_launch(void* const* d_in, const int* in_sizes, int n_in,
                              void* d_out, int out_size, void* d_ws, size_t ws_size,
                              hipStream_t stream)
{
  Params p;
  p.tok  = (const int*)d_in[0];
  p.emb  = (const float*)d_in[1];
  p.pos  = (const float*)d_in[2];
  p.Wq   = (const float*)d_in[3];  p.bq  = (const float*)d_in[4];
  p.Wk   = (const float*)d_in[5];  p.bk  = (const float*)d_in[6];
  p.Wv   = (const float*)d_in[7];  p.bv  = (const float*)d_in[8];
  p.Wo   = (const float*)d_in[9];  p.bo  = (const float*)d_in[10];
  p.W1   = (const float*)d_in[11]; p.b1  = (const float*)d_in[12];
  p.W2   = (const float*)d_in[13]; p.b2  = (const float*)d_in[14];
  p.g1   = (const float*)d_in[15]; p.be1 = (const float*)d_in[16];
  p.g2   = (const float*)d_in[17]; p.be2 = (const float*)d_in[18];
  p.Wout = (const float*)d_in[19]; p.bout = (const float*)d_in[20];

  float* w = (float*)d_ws;
  p.x  = w;            // 32768
  p.qb = p.x  + 32768;
  p.kb = p.qb + 32768;
  p.vb = p.kb + 32768;
  p.ab = p.vb + 32768;
  p.f1 = p.ab + 32768; // 131072
  p.out = (float*)d_out;

  void* args[] = { (void*)&p };
  hipLaunchCooperativeKernel((const void*)k_model, dim3(128), dim3(256),
                             args, 0, stream);
}

// Round 5
// 332.235 us; speedup vs baseline: 1.2339x; 1.2339x over previous
//
#include <hip/hip_runtime.h>
#include <hip/hip_cooperative_groups.h>

namespace cg = cooperative_groups;

#define NBLK 32
#define T 512
#define R 8

// Wf layout (floats): Wq[2*16384] | Wk | Wv | Wo | W1[2*65536] | W2 | Wout[131072]
#define WQ_OFF 0
#define WK_OFF 32768
#define WV_OFF 65536
#define WO_OFF 98304
#define W1_OFF 131072
#define W2_OFF 262144
#define WOUT_OFF 393216

struct Params {
  const int* tok; const float* emb; const float* pos;
  const float* Wq; const float* bq; const float* Wk; const float* bk;
  const float* Wv; const float* bv; const float* Wo; const float* bo;
  const float* W1; const float* b1; const float* W2; const float* b2;
  const float* g1; const float* be1; const float* g2; const float* be2;
  const float* Wout; const float* bout;
  float* Wf; float* kv; float* out;
};

// term value of the reference's l_mul: f(v) = rint(m*2^3) * 2^(2e-3), v=m*2^e.
// (reference applies exp2(pe) twice: once in pf, once in the me-alignment,
//  so each product term is exactly f(x)*f(w) -- verified, absmax 2e-3.)
__device__ __forceinline__ float lmul_tf(float v) {
  int e; float m = frexpf(v, &e);
  return ldexpf(rintf(m * 8.0f), 2 * e - 3);
}

__global__ __launch_bounds__(512, 1) void k_model(Params p) {
  __shared__ float xs [R][132];   // raw x rows (resident all layers)
  __shared__ float xts[R][132];   // f(x) rows
  __shared__ float qs [R][132];   // Q rows (post-bias, raw)
  __shared__ float atb[R][132];   // f(attention out)
  __shared__ float tmp[R][132];   // pre-LN values
  __shared__ float f1s[R][516];   // f(relu(ff1))
  __shared__ float ps [R][4][129];// scores / probs per head

  cg::grid_group grid = cg::this_grid();
  const int bid = blockIdx.x, t = threadIdx.x;
  const int batch = bid >> 4, s0 = (bid & 15) * R;

  // ---------------- Phase 0: transform all weights (grid-partitioned) + embed own rows
  {
    int i4 = bid * T + t;  // float4 index, grid covers 131072 f4 = 524288 floats
    #pragma unroll
    for (int n = 0; n < 8; ++n) {
      int e = (i4 + n * (NBLK * T)) * 4;
      const float* src; int off;
      if (e < 131072)      { int a = e >> 15; src = a==0?p.Wq:(a==1?p.Wk:(a==2?p.Wv:p.Wo)); off = e & 32767; }
      else if (e < 262144) { src = p.W1;   off = e - 131072; }
      else if (e < 393216) { src = p.W2;   off = e - 262144; }
      else                 { src = p.Wout; off = e - 393216; }
      float4 v = *(const float4*)(src + off);
      float4 o;
      o.x = lmul_tf(v.x); o.y = lmul_tf(v.y); o.z = lmul_tf(v.z); o.w = lmul_tf(v.w);
      *(float4*)(p.Wf + e) = o;
    }
    for (int i = t; i < R * 128; i += T) {
      int r = i >> 7, d = i & 127;
      float val = p.emb[p.tok[batch * 128 + s0 + r] * 128 + d] + p.pos[(s0 + r) * 128 + d];
      xs[r][d] = val; xts[r][d] = lmul_tf(val);
    }
  }
  grid.sync();  // sync 1: Wf ready

  // ---------------- QKV projection for layer l: reads xts, writes qs(LDS) + kv(global)
  auto qkv = [&](int l) {
    int r = t & 7, cb = t >> 3;
    float acc[6] = {0, 0, 0, 0, 0, 0};
    const float* wb[6];
    #pragma unroll
    for (int j = 0; j < 6; ++j) {
      int c = cb + 64 * j;                 // 0..383: [Q|K|V] cols
      int proj = c >> 7, d = c & 127;
      wb[j] = p.Wf + (proj == 0 ? WQ_OFF : proj == 1 ? WK_OFF : WV_OFF) + l * 16384 + d * 128;
    }
    for (int k = 0; k < 128; k += 4) {
      float4 xv = *(const float4*)&xts[r][k];
      #pragma unroll
      for (int j = 0; j < 6; ++j) {
        float4 wv = *(const float4*)(wb[j] + k);
        acc[j] += xv.x * wv.x + xv.y * wv.y + xv.z * wv.z + xv.w * wv.w;
      }
    }
    #pragma unroll
    for (int j = 0; j < 6; ++j) {
      int c = cb + 64 * j, proj = c >> 7, d = c & 127;
      float bias = (proj == 0 ? p.bq : proj == 1 ? p.bk : p.bv)[l * 128 + d];
      float vv = acc[j] + bias;
      if (proj == 0) qs[r][d] = vv;
      else p.kv[((l * 2 + (proj - 1)) * 2 + batch) * 16384 + (s0 + r) * 128 + d] = vv;
    }
  };

  auto attn = [&](int l) {
    // scores: wave = row; 16 lanes per head
    {
      int r = t >> 6, h = (t >> 4) & 3, kc = t & 15;
      const float* Kb = p.kv + ((l * 2 + 0) * 2 + batch) * 16384 + h * 32;
      float sc[8] = {0, 0, 0, 0, 0, 0, 0, 0};
      #pragma unroll
      for (int d4 = 0; d4 < 8; ++d4) {
        float4 qv = *(const float4*)&qs[r][h * 32 + d4 * 4];
        #pragma unroll
        for (int m = 0; m < 8; ++m) {
          int s = kc + 16 * m;
          float4 k4 = *(const float4*)(Kb + s * 128 + d4 * 4);
          sc[m] += qv.x * k4.x + qv.y * k4.y + qv.z * k4.z + qv.w * k4.w;
        }
      }
      #pragma unroll
      for (int m = 0; m < 8; ++m)
        ps[r][h][kc + 16 * m] = sc[m] * 0.17677669529663687f;
    }
    __syncthreads();
    // softmax per (row, head): 16-lane groups
    {
      int r = t >> 6, h = (t >> 4) & 3, g = t & 15;
      float v[8]; float mx = -1e30f;
      #pragma unroll
      for (int m = 0; m < 8; ++m) { v[m] = ps[r][h][g + 16 * m]; mx = fmaxf(mx, v[m]); }
      #pragma unroll
      for (int off = 1; off < 16; off <<= 1) mx = fmaxf(mx, __shfl_xor(mx, off));
      float sum = 0.f;
      #pragma unroll
      for (int m = 0; m < 8; ++m) { v[m] = expf(v[m] - mx); sum += v[m]; }
      #pragma unroll
      for (int off = 1; off < 16; off <<= 1) sum += __shfl_xor(sum, off);
      float inv = 1.f / sum;
      #pragma unroll
      for (int m = 0; m < 8; ++m) ps[r][h][g + 16 * m] = v[m] * inv;
    }
    __syncthreads();
    // PV: thread = (row, dim pair); writes f(attn_out)
    {
      int r = t & 7, d0 = (t >> 3) * 2;
      int h = d0 >> 5;  // d0 even => d0,d0+1 in same head
      const float* Vb = p.kv + ((l * 2 + 1) * 2 + batch) * 16384;
      float a0 = 0.f, a1 = 0.f;
      for (int s = 0; s < 128; ++s) {
        float pp = ps[r][h][s];
        float2 vv = *(const float2*)(Vb + s * 128 + d0);
        a0 += pp * vv.x; a1 += pp * vv.y;
      }
      atb[r][d0] = lmul_tf(a0); atb[r][d0 + 1] = lmul_tf(a1);
    }
    __syncthreads();
  };

  // generic LN: tmp -> xs, xts  (wave = row)
  auto lnorm = [&](const float* g, const float* be, int l) {
    int rw = t >> 6, li = t & 63;
    float v0 = tmp[rw][li], v1 = tmp[rw][li + 64];
    float s = v0 + v1, s2 = v0 * v0 + v1 * v1;
    #pragma unroll
    for (int off = 1; off < 64; off <<= 1) {
      s += __shfl_xor(s, off);
      s2 += __shfl_xor(s2, off);
    }
    float mu = s * (1.f / 128.f);
    float var = s2 * (1.f / 128.f) - mu * mu;
    float rr = rsqrtf(var + 1e-5f);
    float n0 = (v0 - mu) * rr * g[l * 128 + li]      + be[l * 128 + li];
    float n1 = (v1 - mu) * rr * g[l * 128 + li + 64] + be[l * 128 + li + 64];
    xs[rw][li] = n0;       xs[rw][li + 64] = n1;
    xts[rw][li] = lmul_tf(n0); xts[rw][li + 64] = lmul_tf(n1);
  };

  auto oproj_ln = [&](int l) {
    int r = t & 7, cb = t >> 3;
    const float* w0 = p.Wf + WO_OFF + l * 16384 + cb * 128;
    const float* w1 = w0 + 64 * 128;
    float a0 = 0.f, a1 = 0.f;
    for (int k = 0; k < 128; k += 4) {
      float4 av = *(const float4*)&atb[r][k];
      float4 v0 = *(const float4*)(w0 + k);
      float4 v1 = *(const float4*)(w1 + k);
      a0 += av.x * v0.x + av.y * v0.y + av.z * v0.z + av.w * v0.w;
      a1 += av.x * v1.x + av.y * v1.y + av.z * v1.z + av.w * v1.w;
    }
    tmp[r][cb]      = a0 + p.bo[l * 128 + cb]      + xs[r][cb];
    tmp[r][cb + 64] = a1 + p.bo[l * 128 + cb + 64] + xs[r][cb + 64];
    __syncthreads();
    lnorm(p.g1, p.be1, l);
    __syncthreads();
  };

  auto ffn = [&](int l) {
    {  // FF1: 512 cols, writes f(relu(.))
      int r = t & 7, cb = t >> 3;
      float acc[8] = {0, 0, 0, 0, 0, 0, 0, 0};
      const float* wbase = p.Wf + W1_OFF + l * 65536 + cb * 128;
      for (int k = 0; k < 128; k += 4) {
        float4 xv = *(const float4*)&xts[r][k];
        #pragma unroll
        for (int j = 0; j < 8; ++j) {
          float4 wv = *(const float4*)(wbase + j * 8192 + k);
          acc[j] += xv.x * wv.x + xv.y * wv.y + xv.z * wv.z + xv.w * wv.w;
        }
      }
      #pragma unroll
      for (int j = 0; j < 8; ++j) {
        int c = cb + 64 * j;
        f1s[r][c] = lmul_tf(fmaxf(acc[j] + p.b1[l * 512 + c], 0.f));
      }
    }
    __syncthreads();
    {  // FF2: K=512 + residual
      int r = t & 7, cb = t >> 3;
      const float* w0 = p.Wf + W2_OFF + l * 65536 + cb * 512;
      const float* w1 = w0 + 64 * 512;
      float a0 = 0.f, a1 = 0.f;
      for (int k = 0; k < 512; k += 4) {
        float4 av = *(const float4*)&f1s[r][k];
        float4 v0 = *(const float4*)(w0 + k);
        float4 v1 = *(const float4*)(w1 + k);
        a0 += av.x * v0.x + av.y * v0.y + av.z * v0.z + av.w * v0.w;
        a1 += av.x * v1.x + av.y * v1.y + av.z * v1.z + av.w * v1.w;
      }
      tmp[r][cb]      = a0 + p.b2[l * 128 + cb]      + xs[r][cb];
      tmp[r][cb + 64] = a1 + p.b2[l * 128 + cb + 64] + xs[r][cb + 64];
    }
    __syncthreads();
    lnorm(p.g2, p.be2, l);
    __syncthreads();
  };

  qkv(0);
  grid.sync();  // sync 2: kv layer 0 ready

  attn(0);
  oproj_ln(0);
  ffn(0);
  qkv(1);
  grid.sync();  // sync 3: kv layer 1 ready

  attn(1);
  oproj_ln(1);
  ffn(1);

  // final head: 1024 cols, row-local, straight to d_out
  {
    int r = t & 7, cb = t >> 3;
    float acc[16];
    #pragma unroll
    for (int j = 0; j < 16; ++j) acc[j] = 0.f;
    const float* wbase = p.Wf + WOUT_OFF + cb * 128;
    for (int k = 0; k < 128; k += 4) {
      float4 xv = *(const float4*)&xts[r][k];
      #pragma unroll
      for (int j = 0; j < 16; ++j) {
        float4 wv = *(const float4*)(wbase + j * 8192 + k);
        acc[j] += xv.x * wv.x + xv.y * wv.y + xv.z * wv.z + xv.w * wv.w;
      }
    }
    #pragma unroll
    for (int j = 0; j < 16; ++j) {
      int c = cb + 64 * j;
      p.out[(batch * 128 + s0 + r) * 1024 + c] = acc[j] + p.bout[c];
    }
  }
}

extern "C" void kernel_launch(void* const* d_in, const int* in_sizes, int n_in,
                              void* d_out, int out_size, void* d_ws, size_t ws_size,
                              hipStream_t stream)
{
  Params p;
  p.tok  = (const int*)d_in[0];
  p.emb  = (const float*)d_in[1];
  p.pos  = (const float*)d_in[2];
  p.Wq   = (const float*)d_in[3];  p.bq  = (const float*)d_in[4];
  p.Wk   = (const float*)d_in[5];  p.bk  = (const float*)d_in[6];
  p.Wv   = (const float*)d_in[7];  p.bv  = (const float*)d_in[8];
  p.Wo   = (const float*)d_in[9];  p.bo  = (const float*)d_in[10];
  p.W1   = (const float*)d_in[11]; p.b1  = (const float*)d_in[12];
  p.W2   = (const float*)d_in[13]; p.b2  = (const float*)d_in[14];
  p.g1   = (const float*)d_in[15]; p.be1 = (const float*)d_in[16];
  p.g2   = (const float*)d_in[17]; p.be2 = (const float*)d_in[18];
  p.Wout = (const float*)d_in[19]; p.bout = (const float*)d_in[20];

  float* w = (float*)d_ws;
  p.Wf = w;                 // 524288 floats (2 MB)
  p.kv = w + 524288;        // 131072 floats (512 KB): [l][K/V][b][s][d]
  p.out = (float*)d_out;

  void* args[] = { (void*)&p };
  hipLaunchCooperativeKernel((const void*)k_model, dim3(NBLK), dim3(T),
                             args, 0, stream);
}

// Round 6
// 308.948 us; speedup vs baseline: 1.3269x; 1.0754x over previous
//
#include <hip/hip_runtime.h>
#include <hip/hip_cooperative_groups.h>

namespace cg = cooperative_groups;

#define NBLK 32
#define T 512
#define R 8

// Wf layout (floats), all matrices TRANSPOSED to k-major WT[k][c]:
// WqT[2][128][128] | WkT | WvT | WoT | W1T[2][128][512] | W2T[2][512][128] | WoutT[128][1024]
#define WQ_OFF 0
#define WK_OFF 32768
#define WV_OFF 65536
#define WO_OFF 98304
#define W1_OFF 131072
#define W2_OFF 262144
#define WOUT_OFF 393216

struct Params {
  const int* tok; const float* emb; const float* pos;
  const float* Wq; const float* bq; const float* Wk; const float* bk;
  const float* Wv; const float* bv; const float* Wo; const float* bo;
  const float* W1; const float* b1; const float* W2; const float* b2;
  const float* g1; const float* be1; const float* g2; const float* be2;
  const float* Wout; const float* bout;
  float* Wf; float* kv; float* out;
};

// f(v) = rint(m*2^3) * 2^(2e-3), v = m*2^e, 0.5<=|m|<1.  Each l_mul product
// term is exactly f(x)*f(w) (exp2 alignment is a numeric no-op). Verified r1/r5.
__device__ __forceinline__ float lmul_tf(float v) {
  int e; float m = frexpf(v, &e);
  return ldexpf(rintf(m * 8.0f), 2 * e - 3);
}

__global__ __launch_bounds__(512, 1) void k_model(Params p) {
  __shared__ float xs [R][132];   // raw x rows (resident all layers)
  __shared__ float xts[R][132];   // f(x) rows
  __shared__ float qs [R][132];   // Q rows (post-bias, raw)
  __shared__ float atb[R][132];   // f(attention out)
  __shared__ float tmp[R][132];   // pre-LN values / FF2 partials
  __shared__ float f1s[R][516];   // f(relu(ff1))
  __shared__ float ps [R][4][129];// probs per head
  __shared__ float scratch[4224]; // transpose tile [64][65] / K chunk [32][132]

  cg::grid_group grid = cg::this_grid();
  const int bid = blockIdx.x, t = threadIdx.x;
  const int batch = bid >> 4, s0 = (bid & 15) * R;
  const int lane = t & 63, w = t >> 6;      // wave id 0..7
  const int c4 = lane & 7, r = lane >> 3;   // matmul mapping: 8 cols x 8 rows

  // ---------------- Phase 0: transform+TRANSPOSE all weights (128 64x64 tiles,
  // 4 per block) + embed own rows
  {
    for (int i = 0; i < 4; ++i) {
      int tid = bid * 4 + i;   // 0..127
      const float* src; float* dst; int srcK, dstC, cc0, kk0;
      if (tid < 32) {
        int m = tid >> 3, rem = tid & 7, l = rem >> 2, ts = rem & 3;
        cc0 = (ts >> 1) * 64; kk0 = (ts & 1) * 64;
        src = (m == 0 ? p.Wq : m == 1 ? p.Wk : m == 2 ? p.Wv : p.Wo) + l * 16384;
        dst = p.Wf + m * 32768 + l * 16384;
        srcK = 128; dstC = 128;
      } else if (tid < 64) {
        int rm = tid - 32, l = rm >> 4, ts = rm & 15;
        cc0 = (ts >> 1) * 64; kk0 = (ts & 1) * 64;
        src = p.W1 + l * 65536; dst = p.Wf + W1_OFF + l * 65536;
        srcK = 128; dstC = 512;
      } else if (tid < 96) {
        int rm = tid - 64, l = rm >> 4, ts = rm & 15;
        cc0 = (ts >> 3) * 64; kk0 = (ts & 7) * 64;
        src = p.W2 + l * 65536; dst = p.Wf + W2_OFF + l * 65536;
        srcK = 512; dstC = 128;
      } else {
        int rm = tid - 96, ts = rm & 31;
        cc0 = (ts >> 1) * 64; kk0 = (ts & 1) * 64;
        src = p.Wout; dst = p.Wf + WOUT_OFF;
        srcK = 128; dstC = 1024;
      }
      #pragma unroll
      for (int u = 0; u < 2; ++u) {
        int idx = t + u * 512;            // 0..1023 float4s
        int row = idx >> 4, col4 = idx & 15;
        float4 v = *(const float4*)(src + (size_t)(cc0 + row) * srcK + kk0 + col4 * 4);
        float* dl = &scratch[row * 65 + col4 * 4];
        dl[0] = lmul_tf(v.x); dl[1] = lmul_tf(v.y);
        dl[2] = lmul_tf(v.z); dl[3] = lmul_tf(v.w);
      }
      __syncthreads();
      #pragma unroll
      for (int u = 0; u < 2; ++u) {
        int idx = t + u * 512;
        int krow = idx >> 4, cc4 = idx & 15;
        float4 o;
        o.x = scratch[(cc4 * 4 + 0) * 65 + krow];
        o.y = scratch[(cc4 * 4 + 1) * 65 + krow];
        o.z = scratch[(cc4 * 4 + 2) * 65 + krow];
        o.w = scratch[(cc4 * 4 + 3) * 65 + krow];
        *(float4*)(dst + (size_t)(kk0 + krow) * dstC + cc0 + cc4 * 4) = o;
      }
      __syncthreads();
    }
    for (int i = t; i < R * 128; i += T) {
      int rr = i >> 7, d = i & 127;
      float val = p.emb[p.tok[batch * 128 + s0 + rr] * 128 + d] + p.pos[(s0 + rr) * 128 + d];
      xs[rr][d] = val; xts[rr][d] = lmul_tf(val);
    }
  }
  grid.sync();  // sync 1: Wf ready

  // QKV: 12 col-strips of 32 (Q:0-3, K:4-7, V:8-11). wave w -> strips {w, w+8}
  auto qkv = [&](int l) {
    for (int sIdx = w; sIdx < 12; sIdx += 8) {
      int proj = sIdx >> 2;
      int c = (sIdx & 3) * 32 + c4 * 4;
      const float* WT = p.Wf + (proj == 0 ? WQ_OFF : proj == 1 ? WK_OFF : WV_OFF) + l * 16384;
      float4 acc = {0.f, 0.f, 0.f, 0.f};
      #pragma unroll 8
      for (int k = 0; k < 128; ++k) {
        float4 w4 = *(const float4*)(WT + k * 128 + c);
        float xk = xts[r][k];
        acc.x += xk * w4.x; acc.y += xk * w4.y;
        acc.z += xk * w4.z; acc.w += xk * w4.w;
      }
      const float* bb = (proj == 0 ? p.bq : proj == 1 ? p.bk : p.bv) + l * 128;
      acc.x += bb[c]; acc.y += bb[c + 1]; acc.z += bb[c + 2]; acc.w += bb[c + 3];
      if (proj == 0) *(float4*)&qs[r][c] = acc;
      else *(float4*)(p.kv + ((l * 2 + (proj - 1)) * 2 + batch) * 16384
                      + (s0 + r) * 128 + c) = acc;
    }
  };

  auto attn = [&](int l) {
    const float* Kb = p.kv + ((l * 2 + 0) * 2 + batch) * 16384;
    const float* Vb = p.kv + ((l * 2 + 1) * 2 + batch) * 16384;
    int rq = t >> 6, h = (t >> 4) & 3, kc = t & 15;
    // hoist Q fragment (r,h): 8 float4
    float4 qv[8];
    #pragma unroll
    for (int d4 = 0; d4 < 8; ++d4) qv[d4] = *(const float4*)&qs[rq][h * 32 + d4 * 4];
    float sc[8];
    for (int chunk = 0; chunk < 4; ++chunk) {
      #pragma unroll
      for (int u = 0; u < 2; ++u) {
        int idx = t + u * 512;            // 1024 float4 = 32 rows x 128
        int row = idx >> 5, col4 = idx & 31;
        *(float4*)&scratch[row * 132 + col4 * 4] =
            *(const float4*)(Kb + (chunk * 32 + row) * 128 + col4 * 4);
      }
      __syncthreads();
      #pragma unroll
      for (int m2 = 0; m2 < 2; ++m2) {
        int sl = kc + 16 * m2;
        float a = 0.f;
        #pragma unroll
        for (int d4 = 0; d4 < 8; ++d4) {
          float4 k4 = *(const float4*)&scratch[sl * 132 + h * 32 + d4 * 4];
          a += qv[d4].x * k4.x + qv[d4].y * k4.y + qv[d4].z * k4.z + qv[d4].w * k4.w;
        }
        sc[chunk * 2 + m2] = a * 0.17677669529663687f;  // s = kc + 16*(2chunk+m2)
      }
      __syncthreads();
    }
    // softmax over the 16-lane (rq,h) group; sc[m] holds s = kc + 16m
    float mx = -1e30f;
    #pragma unroll
    for (int m = 0; m < 8; ++m) mx = fmaxf(mx, sc[m]);
    #pragma unroll
    for (int off = 1; off < 16; off <<= 1) mx = fmaxf(mx, __shfl_xor(mx, off));
    float sum = 0.f;
    #pragma unroll
    for (int m = 0; m < 8; ++m) { sc[m] = expf(sc[m] - mx); sum += sc[m]; }
    #pragma unroll
    for (int off = 1; off < 16; off <<= 1) sum += __shfl_xor(sum, off);
    float inv = 1.f / sum;
    #pragma unroll
    for (int m = 0; m < 8; ++m) ps[rq][h][kc + 16 * m] = sc[m] * inv;
    __syncthreads();
    // PV: thread = (row r2, dim pair d0)
    {
      int r2 = t & 7, d0 = (t >> 3) * 2;
      int hh = d0 >> 5;
      float a0 = 0.f, a1 = 0.f;
      for (int s = 0; s < 128; ++s) {
        float pp = ps[r2][hh][s];
        float2 vv = *(const float2*)(Vb + s * 128 + d0);
        a0 += pp * vv.x; a1 += pp * vv.y;
      }
      atb[r2][d0] = lmul_tf(a0); atb[r2][d0 + 1] = lmul_tf(a1);
    }
    __syncthreads();
  };

  // LN: tmp -> xs, xts (wave = row)
  auto lnorm = [&](const float* g, const float* be, int l) {
    int rw = t >> 6, li = t & 63;
    float v0 = tmp[rw][li], v1 = tmp[rw][li + 64];
    float s = v0 + v1, s2 = v0 * v0 + v1 * v1;
    #pragma unroll
    for (int off = 1; off < 64; off <<= 1) {
      s += __shfl_xor(s, off);
      s2 += __shfl_xor(s2, off);
    }
    float mu = s * (1.f / 128.f);
    float var = s2 * (1.f / 128.f) - mu * mu;
    float rr2 = rsqrtf(var + 1e-5f);
    float n0 = (v0 - mu) * rr2 * g[l * 128 + li]      + be[l * 128 + li];
    float n1 = (v1 - mu) * rr2 * g[l * 128 + li + 64] + be[l * 128 + li + 64];
    xs[rw][li] = n0;           xs[rw][li + 64] = n1;
    xts[rw][li] = lmul_tf(n0); xts[rw][li + 64] = lmul_tf(n1);
  };

  auto oproj_ln = [&](int l) {
    if (w < 4) {                        // C=128: 4 strips
      int c = w * 32 + c4 * 4;
      const float* WT = p.Wf + WO_OFF + l * 16384;
      float4 acc = {0.f, 0.f, 0.f, 0.f};
      #pragma unroll 8
      for (int k = 0; k < 128; ++k) {
        float4 w4 = *(const float4*)(WT + k * 128 + c);
        float xk = atb[r][k];
        acc.x += xk * w4.x; acc.y += xk * w4.y;
        acc.z += xk * w4.z; acc.w += xk * w4.w;
      }
      const float* bb = p.bo + l * 128;
      tmp[r][c]     = acc.x + bb[c]     + xs[r][c];
      tmp[r][c + 1] = acc.y + bb[c + 1] + xs[r][c + 1];
      tmp[r][c + 2] = acc.z + bb[c + 2] + xs[r][c + 2];
      tmp[r][c + 3] = acc.w + bb[c + 3] + xs[r][c + 3];
    }
    __syncthreads();
    lnorm(p.g1, p.be1, l);
    __syncthreads();
  };

  auto ffn = [&](int l) {
    {  // FF1: C=512 -> 16 strips, 2 per wave
      const float* WT = p.Wf + W1_OFF + l * 65536;
      for (int sIdx = w; sIdx < 16; sIdx += 8) {
        int c = sIdx * 32 + c4 * 4;
        float4 acc = {0.f, 0.f, 0.f, 0.f};
        #pragma unroll 8
        for (int k = 0; k < 128; ++k) {
          float4 w4 = *(const float4*)(WT + k * 512 + c);
          float xk = xts[r][k];
          acc.x += xk * w4.x; acc.y += xk * w4.y;
          acc.z += xk * w4.z; acc.w += xk * w4.w;
        }
        const float* bb = p.b1 + l * 512;
        f1s[r][c]     = lmul_tf(fmaxf(acc.x + bb[c],     0.f));
        f1s[r][c + 1] = lmul_tf(fmaxf(acc.y + bb[c + 1], 0.f));
        f1s[r][c + 2] = lmul_tf(fmaxf(acc.z + bb[c + 2], 0.f));
        f1s[r][c + 3] = lmul_tf(fmaxf(acc.w + bb[c + 3], 0.f));
      }
    }
    __syncthreads();
    {  // FF2: C=128, K=512 -> 4 strips x 2 k-halves
      int strip = w & 3, kh = w >> 2;
      int c = strip * 32 + c4 * 4;
      const float* WT = p.Wf + W2_OFF + l * 65536;
      float4 acc = {0.f, 0.f, 0.f, 0.f};
      #pragma unroll 8
      for (int k = kh * 256; k < kh * 256 + 256; ++k) {
        float4 w4 = *(const float4*)(WT + k * 128 + c);
        float xk = f1s[r][k];
        acc.x += xk * w4.x; acc.y += xk * w4.y;
        acc.z += xk * w4.z; acc.w += xk * w4.w;
      }
      if (kh == 0) *(float4*)&tmp[r][c] = acc;
      __syncthreads();
      if (kh == 1) {
        const float* bb = p.b2 + l * 128;
        float4 t0 = *(const float4*)&tmp[r][c];
        tmp[r][c]     = t0.x + acc.x + bb[c]     + xs[r][c];
        tmp[r][c + 1] = t0.y + acc.y + bb[c + 1] + xs[r][c + 1];
        tmp[r][c + 2] = t0.z + acc.z + bb[c + 2] + xs[r][c + 2];
        tmp[r][c + 3] = t0.w + acc.w + bb[c + 3] + xs[r][c + 3];
      }
    }
    __syncthreads();
    lnorm(p.g2, p.be2, l);
    __syncthreads();
  };

  qkv(0);
  grid.sync();  // sync 2: kv layer 0 ready

  attn(0);
  oproj_ln(0);
  ffn(0);
  qkv(1);
  grid.sync();  // sync 3: kv layer 1 ready

  attn(1);
  oproj_ln(1);
  ffn(1);

  // final head: C=1024 -> 32 strips, 4 per wave
  {
    const float* WT = p.Wf + WOUT_OFF;
    for (int sIdx = w; sIdx < 32; sIdx += 8) {
      int c = sIdx * 32 + c4 * 4;
      float4 acc = {0.f, 0.f, 0.f, 0.f};
      #pragma unroll 8
      for (int k = 0; k < 128; ++k) {
        float4 w4 = *(const float4*)(WT + k * 1024 + c);
        float xk = xts[r][k];
        acc.x += xk * w4.x; acc.y += xk * w4.y;
        acc.z += xk * w4.z; acc.w += xk * w4.w;
      }
      float4 o;
      o.x = acc.x + p.bout[c];     o.y = acc.y + p.bout[c + 1];
      o.z = acc.z + p.bout[c + 2]; o.w = acc.w + p.bout[c + 3];
      *(float4*)(p.out + (size_t)(batch * 128 + s0 + r) * 1024 + c) = o;
    }
  }
}

extern "C" void kernel_launch(void* const* d_in, const int* in_sizes, int n_in,
                              void* d_out, int out_size, void* d_ws, size_t ws_size,
                              hipStream_t stream)
{
  Params p;
  p.tok  = (const int*)d_in[0];
  p.emb  = (const float*)d_in[1];
  p.pos  = (const float*)d_in[2];
  p.Wq   = (const float*)d_in[3];  p.bq  = (const float*)d_in[4];
  p.Wk   = (const float*)d_in[5];  p.bk  = (const float*)d_in[6];
  p.Wv   = (const float*)d_in[7];  p.bv  = (const float*)d_in[8];
  p.Wo   = (const float*)d_in[9];  p.bo  = (const float*)d_in[10];
  p.W1   = (const float*)d_in[11]; p.b1  = (const float*)d_in[12];
  p.W2   = (const float*)d_in[13]; p.b2  = (const float*)d_in[14];
  p.g1   = (const float*)d_in[15]; p.be1 = (const float*)d_in[16];
  p.g2   = (const float*)d_in[17]; p.be2 = (const float*)d_in[18];
  p.Wout = (const float*)d_in[19]; p.bout = (const float*)d_in[20];

  float* w = (float*)d_ws;
  p.Wf = w;                 // 524288 floats (2 MB), transposed k-major
  p.kv = w + 524288;        // 131072 floats: [l][K/V][b][s][d]
  p.out = (float*)d_out;

  void* args[] = { (void*)&p };
  hipLaunchCooperativeKernel((const void*)k_model, dim3(NBLK), dim3(T),
                             args, 0, stream);
}

// Round 7
// 239.780 us; speedup vs baseline: 1.7096x; 1.2885x over previous
//
#include <hip/hip_runtime.h>
#include <hip/hip_cooperative_groups.h>

namespace cg = cooperative_groups;

#define NBLK 32
#define TPB 512

// ws weight layout (floats), all k-major (transposed), QKV column-merged:
// WqkvT[l][128][384] | WoT[l][128][128] | W1T[l][128][512] | W2T[l][512][128] | WoutT[128][1024]
#define WQKV_OFF 0
#define WO_OFF   98304
#define W1_OFF   131072
#define W2_OFF   262144
#define WOUT_OFF 393216

struct Params {
  const int* tok; const float* emb; const float* pos;
  const float* Wq; const float* bq; const float* Wk; const float* bk;
  const float* Wv; const float* bv; const float* Wo; const float* bo;
  const float* W1; const float* b1; const float* W2; const float* b2;
  const float* g1; const float* be1; const float* g2; const float* be2;
  const float* Wout; const float* bout;
  float* Wf; float* kv; float* out;
};

// f(v) = rint(m*8)*2^(2e-3), v=m*2^e. Each l_mul term is exactly f(x)*f(w).
__device__ __forceinline__ float lmul_tf(float v) {
  int e; float m = frexpf(v, &e);
  return ldexpf(rintf(m * 8.0f), 2 * e - 3);
}
__device__ __forceinline__ float f4_at(const float4 v, int i) {
  switch (i & 3) { case 0: return v.x; case 1: return v.y; case 2: return v.z; default: return v.w; }
}
#define FMA4(acc, s, v) { acc.x += (s)*(v).x; acc.y += (s)*(v).y; acc.z += (s)*(v).z; acc.w += (s)*(v).w; }

__global__ __launch_bounds__(512, 1) void k_model(Params p) {
  __shared__ __align__(16) float xs [8][132];
  __shared__ __align__(16) float xts[8][132];
  __shared__ __align__(16) float qs [8][132];
  __shared__ __align__(16) float atb[8][132];
  __shared__ __align__(16) float tmp[8][132];
  __shared__ __align__(16) float f1s[8][516];
  __shared__ __align__(16) float ps [8][4][129];
  __shared__ float4 stage4[4096];                  // 64 KB dbuf / scratch
  __shared__ __align__(16) float cmb[3072];        // k-split combine
  float* stage = (float*)stage4;

  cg::grid_group grid = cg::this_grid();
  const int bid = blockIdx.x, t = threadIdx.x;
  const int batch = bid >> 4, s0 = (bid & 15) * 8;
  const int lane = t & 63, w = t >> 6;
  const int c4 = lane & 7, r = lane >> 3;

  // ---------------- phase 0: transform + transpose weights (4 64x64 tiles/block); embed
  {
    for (int i = 0; i < 4; ++i) {
      int tid = bid * 4 + i;
      const float* src; float* dst; int srcK, dstC, cc0, kk0, dcol0;
      if (tid < 32) {
        int m = tid >> 3, rem = tid & 7, l = rem >> 2, ts = rem & 3;
        cc0 = (ts >> 1) * 64; kk0 = (ts & 1) * 64;
        src = (m == 0 ? p.Wq : m == 1 ? p.Wk : m == 2 ? p.Wv : p.Wo) + l * 16384;
        srcK = 128;
        if (m < 3) { dst = p.Wf + WQKV_OFF + l * 49152; dstC = 384; dcol0 = m * 128 + cc0; }
        else       { dst = p.Wf + WO_OFF   + l * 16384; dstC = 128; dcol0 = cc0; }
      } else if (tid < 64) {
        int rm = tid - 32, l = rm >> 4, ts = rm & 15;
        cc0 = (ts >> 1) * 64; kk0 = (ts & 1) * 64;
        src = p.W1 + l * 65536; dst = p.Wf + W1_OFF + l * 65536;
        srcK = 128; dstC = 512; dcol0 = cc0;
      } else if (tid < 96) {
        int rm = tid - 64, l = rm >> 4, ts = rm & 15;
        cc0 = (ts >> 3) * 64; kk0 = (ts & 7) * 64;
        src = p.W2 + l * 65536; dst = p.Wf + W2_OFF + l * 65536;
        srcK = 512; dstC = 128; dcol0 = cc0;
      } else {
        int rm = tid - 96, ts = rm & 31;
        cc0 = (ts >> 1) * 64; kk0 = (ts & 1) * 64;
        src = p.Wout; dst = p.Wf + WOUT_OFF;
        srcK = 128; dstC = 1024; dcol0 = cc0;
      }
      #pragma unroll
      for (int u = 0; u < 2; ++u) {
        int idx = t + u * 512, row = idx >> 4, col4 = idx & 15;
        float4 v = *(const float4*)(src + (size_t)(cc0 + row) * srcK + kk0 + col4 * 4);
        float* dl = &stage[row * 65 + col4 * 4];
        dl[0] = lmul_tf(v.x); dl[1] = lmul_tf(v.y); dl[2] = lmul_tf(v.z); dl[3] = lmul_tf(v.w);
      }
      __syncthreads();
      #pragma unroll
      for (int u = 0; u < 2; ++u) {
        int idx = t + u * 512, krow = idx >> 4, cc4 = idx & 15;
        float4 o;
        o.x = stage[(cc4 * 4 + 0) * 65 + krow];
        o.y = stage[(cc4 * 4 + 1) * 65 + krow];
        o.z = stage[(cc4 * 4 + 2) * 65 + krow];
        o.w = stage[(cc4 * 4 + 3) * 65 + krow];
        *(float4*)(dst + (size_t)(kk0 + krow) * dstC + dcol0 + cc4 * 4) = o;
      }
      __syncthreads();
    }
    for (int i = t; i < 8 * 128; i += TPB) {
      int rr = i >> 7, d = i & 127;
      float val = p.emb[p.tok[batch * 128 + s0 + rr] * 128 + d] + p.pos[(s0 + rr) * 128 + d];
      xs[rr][d] = val; xts[rr][d] = lmul_tf(val);
    }
  }
  grid.sync();  // sync 1: Wf ready

  // ---------------- QKV: WT[128][384], KC=16, 8 chunks, ksplit; jobs: strips {sA,sB,sC} x half hf
  auto qkv = [&](int l) {
    const float4* g4 = (const float4*)(p.Wf + WQKV_OFF + l * 49152);
    const int sA = w >> 1, sB = sA + 4, sC = sA + 8, hf = w & 1;
    const int slot = w * 192 + lane;
    float4 L0 = g4[slot], L1 = g4[slot + 64], L2 = g4[slot + 128];
    float4 aA = {0,0,0,0}, aB = {0,0,0,0}, aC = {0,0,0,0};
    for (int c = 0; c < 8; ++c) {
      float4* bw = stage4 + (c & 1) * 1536;
      bw[slot] = L0; bw[slot + 64] = L1; bw[slot + 128] = L2;
      if (c < 7) { int b = (c + 1) * 1536 + slot; L0 = g4[b]; L1 = g4[b + 64]; L2 = g4[b + 128]; }
      asm volatile("s_waitcnt lgkmcnt(0)" ::: "memory");
      __builtin_amdgcn_s_barrier();
      const float* bc = stage + (c & 1) * 6144;
      float4 xf0 = *(const float4*)&xts[r][c * 16 + hf * 8];
      float4 xf1 = *(const float4*)&xts[r][c * 16 + hf * 8 + 4];
      #pragma unroll
      for (int kk = 0; kk < 8; ++kk) {
        float xk = (kk < 4) ? f4_at(xf0, kk) : f4_at(xf1, kk);
        const float* row = bc + (hf * 8 + kk) * 384 + c4 * 4;
        float4 wA = *(const float4*)(row + sA * 32);
        float4 wB = *(const float4*)(row + sB * 32);
        float4 wC = *(const float4*)(row + sC * 32);
        FMA4(aA, xk, wA); FMA4(aB, xk, wB); FMA4(aC, xk, wC);
      }
      __builtin_amdgcn_s_barrier();
    }
    if (hf == 0) {
      *(float4*)&cmb[((sA * 8 + r) * 8 + c4) * 4] = aA;
      *(float4*)&cmb[((sB * 8 + r) * 8 + c4) * 4] = aB;
      *(float4*)&cmb[((sC * 8 + r) * 8 + c4) * 4] = aC;
    }
    __syncthreads();
    if (hf == 1) {
      #pragma unroll
      for (int j = 0; j < 3; ++j) {
        int s = (j == 0) ? sA : (j == 1) ? sB : sC;
        float4 acc = (j == 0) ? aA : (j == 1) ? aB : aC;
        float4 part = *(const float4*)&cmb[((s * 8 + r) * 8 + c4) * 4];
        int proj = s >> 2, cip = (s & 3) * 32 + c4 * 4;
        const float* bb = (proj == 0 ? p.bq : proj == 1 ? p.bk : p.bv) + l * 128 + cip;
        acc.x += part.x + bb[0]; acc.y += part.y + bb[1];
        acc.z += part.z + bb[2]; acc.w += part.w + bb[3];
        if (proj == 0) *(float4*)&qs[r][cip] = acc;
        else *(float4*)(p.kv + (size_t)((l * 2 + (proj - 1)) * 2 + batch) * 16384
                        + (s0 + r) * 128 + cip) = acc;
      }
    }
    __syncthreads();
  };

  // ---------------- attention (K and V staged through LDS in 32-row chunks)
  auto attn = [&](int l) {
    const float* Kb = p.kv + (size_t)((l * 2 + 0) * 2 + batch) * 16384;
    const float* Vb = p.kv + (size_t)((l * 2 + 1) * 2 + batch) * 16384;
    int rq = t >> 6, h = (t >> 4) & 3, kc = t & 15;
    float4 qv[8];
    #pragma unroll
    for (int d4 = 0; d4 < 8; ++d4) qv[d4] = *(const float4*)&qs[rq][h * 32 + d4 * 4];
    float sc[8];
    for (int chunk = 0; chunk < 4; ++chunk) {
      #pragma unroll
      for (int u = 0; u < 2; ++u) {
        int idx = t + u * 512, row = idx >> 5, col4 = idx & 31;
        *(float4*)&stage[row * 132 + col4 * 4] =
            *(const float4*)(Kb + (chunk * 32 + row) * 128 + col4 * 4);
      }
      __syncthreads();
      #pragma unroll
      for (int m2 = 0; m2 < 2; ++m2) {
        int sl = kc + 16 * m2;
        float a = 0.f;
        #pragma unroll
        for (int d4 = 0; d4 < 8; ++d4) {
          float4 k4 = *(const float4*)&stage[sl * 132 + h * 32 + d4 * 4];
          a += qv[d4].x * k4.x + qv[d4].y * k4.y + qv[d4].z * k4.z + qv[d4].w * k4.w;
        }
        sc[chunk * 2 + m2] = a * 0.17677669529663687f;
      }
      __syncthreads();
    }
    float mx = -1e30f;
    #pragma unroll
    for (int m = 0; m < 8; ++m) mx = fmaxf(mx, sc[m]);
    #pragma unroll
    for (int off = 1; off < 16; off <<= 1) mx = fmaxf(mx, __shfl_xor(mx, off));
    float sum = 0.f;
    #pragma unroll
    for (int m = 0; m < 8; ++m) { sc[m] = expf(sc[m] - mx); sum += sc[m]; }
    #pragma unroll
    for (int off = 1; off < 16; off <<= 1) sum += __shfl_xor(sum, off);
    float inv = 1.f / sum;
    #pragma unroll
    for (int m = 0; m < 8; ++m) ps[rq][h][kc + 16 * m] = sc[m] * inv;
    __syncthreads();
    // PV with V staged
    int r2 = t & 7, d0 = (t >> 3) * 2, hh = d0 >> 5;
    float a0 = 0.f, a1 = 0.f;
    for (int ch = 0; ch < 4; ++ch) {
      #pragma unroll
      for (int u = 0; u < 2; ++u) {
        int idx = t + u * 512, row = idx >> 5, col4 = idx & 31;
        *(float4*)&stage[row * 132 + col4 * 4] =
            *(const float4*)(Vb + (ch * 32 + row) * 128 + col4 * 4);
      }
      __syncthreads();
      #pragma unroll
      for (int ss = 0; ss < 32; ++ss) {
        float pp = ps[r2][hh][ch * 32 + ss];
        a0 += pp * stage[ss * 132 + d0];
        a1 += pp * stage[ss * 132 + d0 + 1];
      }
      __syncthreads();
    }
    atb[r2][d0] = lmul_tf(a0); atb[r2][d0 + 1] = lmul_tf(a1);
    __syncthreads();
  };

  auto lnorm = [&](const float* g, const float* be, int l) {
    int rw = t >> 6, li = t & 63;
    float v0 = tmp[rw][li], v1 = tmp[rw][li + 64];
    float s = v0 + v1, s2 = v0 * v0 + v1 * v1;
    #pragma unroll
    for (int off = 1; off < 64; off <<= 1) { s += __shfl_xor(s, off); s2 += __shfl_xor(s2, off); }
    float mu = s * (1.f / 128.f);
    float var = s2 * (1.f / 128.f) - mu * mu;
    float rr2 = rsqrtf(var + 1e-5f);
    float n0 = (v0 - mu) * rr2 * g[l * 128 + li]      + be[l * 128 + li];
    float n1 = (v1 - mu) * rr2 * g[l * 128 + li + 64] + be[l * 128 + li + 64];
    xs[rw][li] = n0;           xs[rw][li + 64] = n1;
    xts[rw][li] = lmul_tf(n0); xts[rw][li + 64] = lmul_tf(n1);
  };

  // ---------------- O-proj + LN: WT[128][128], KC=64, 2 chunks, ksplit
  auto oproj_ln = [&](int l) {
    const float4* g4 = (const float4*)(p.Wf + WO_OFF + l * 16384);
    const int st = w >> 1, hf = w & 1;
    const int slot = w * 256 + lane;
    float4 L0 = g4[slot], L1 = g4[slot + 64], L2 = g4[slot + 128], L3 = g4[slot + 192];
    float4 acc = {0,0,0,0};
    for (int c = 0; c < 2; ++c) {
      float4* bw = stage4 + (c & 1) * 2048;
      bw[slot] = L0; bw[slot + 64] = L1; bw[slot + 128] = L2; bw[slot + 192] = L3;
      if (c < 1) { int b = 2048 + slot; L0 = g4[b]; L1 = g4[b + 64]; L2 = g4[b + 128]; L3 = g4[b + 192]; }
      asm volatile("s_waitcnt lgkmcnt(0)" ::: "memory");
      __builtin_amdgcn_s_barrier();
      const float* bc = stage + (c & 1) * 8192;
      float4 xf[8];
      #pragma unroll
      for (int j = 0; j < 8; ++j) xf[j] = *(const float4*)&atb[r][c * 64 + hf * 32 + j * 4];
      #pragma unroll
      for (int kk = 0; kk < 32; ++kk) {
        float xk = f4_at(xf[kk >> 2], kk);
        float4 wv = *(const float4*)(bc + (hf * 32 + kk) * 128 + st * 32 + c4 * 4);
        FMA4(acc, xk, wv);
      }
      __builtin_amdgcn_s_barrier();
    }
    if (hf == 0) *(float4*)&cmb[((st * 8 + r) * 8 + c4) * 4] = acc;
    __syncthreads();
    if (hf == 1) {
      float4 part = *(const float4*)&cmb[((st * 8 + r) * 8 + c4) * 4];
      int col = st * 32 + c4 * 4;
      const float* bb = p.bo + l * 128 + col;
      float4 xr = *(const float4*)&xs[r][col];
      tmp[r][col + 0] = acc.x + part.x + bb[0] + xr.x;
      tmp[r][col + 1] = acc.y + part.y + bb[1] + xr.y;
      tmp[r][col + 2] = acc.z + part.z + bb[2] + xr.z;
      tmp[r][col + 3] = acc.w + part.w + bb[3] + xr.w;
    }
    __syncthreads();
    lnorm(p.g1, p.be1, l);
    __syncthreads();
  };

  // ---------------- FFN
  auto ffn = [&](int l) {
    { // FF1: WT[128][512], KC=16, 8 chunks, strips {w, w+8}
      const float4* g4 = (const float4*)(p.Wf + W1_OFF + l * 65536);
      const int slot = w * 256 + lane;
      float4 L0 = g4[slot], L1 = g4[slot + 64], L2 = g4[slot + 128], L3 = g4[slot + 192];
      float4 aA = {0,0,0,0}, aB = {0,0,0,0};
      for (int c = 0; c < 8; ++c) {
        float4* bw = stage4 + (c & 1) * 2048;
        bw[slot] = L0; bw[slot + 64] = L1; bw[slot + 128] = L2; bw[slot + 192] = L3;
        if (c < 7) { int b = (c + 1) * 2048 + slot; L0 = g4[b]; L1 = g4[b + 64]; L2 = g4[b + 128]; L3 = g4[b + 192]; }
        asm volatile("s_waitcnt lgkmcnt(0)" ::: "memory");
        __builtin_amdgcn_s_barrier();
        const float* bc = stage + (c & 1) * 8192;
        float4 xf[4];
        #pragma unroll
        for (int j = 0; j < 4; ++j) xf[j] = *(const float4*)&xts[r][c * 16 + j * 4];
        #pragma unroll
        for (int kk = 0; kk < 16; ++kk) {
          float xk = f4_at(xf[kk >> 2], kk);
          const float* row = bc + kk * 512 + c4 * 4;
          float4 wA = *(const float4*)(row + w * 32);
          float4 wB = *(const float4*)(row + (w + 8) * 32);
          FMA4(aA, xk, wA); FMA4(aB, xk, wB);
        }
        __builtin_amdgcn_s_barrier();
      }
      const float* b1p = p.b1 + l * 512;
      int colA = w * 32 + c4 * 4, colB = (w + 8) * 32 + c4 * 4;
      float4 oA, oB;
      oA.x = lmul_tf(fmaxf(aA.x + b1p[colA + 0], 0.f));
      oA.y = lmul_tf(fmaxf(aA.y + b1p[colA + 1], 0.f));
      oA.z = lmul_tf(fmaxf(aA.z + b1p[colA + 2], 0.f));
      oA.w = lmul_tf(fmaxf(aA.w + b1p[colA + 3], 0.f));
      oB.x = lmul_tf(fmaxf(aB.x + b1p[colB + 0], 0.f));
      oB.y = lmul_tf(fmaxf(aB.y + b1p[colB + 1], 0.f));
      oB.z = lmul_tf(fmaxf(aB.z + b1p[colB + 2], 0.f));
      oB.w = lmul_tf(fmaxf(aB.w + b1p[colB + 3], 0.f));
      *(float4*)&f1s[r][colA] = oA;
      *(float4*)&f1s[r][colB] = oB;
    }
    __syncthreads();
    { // FF2: WT[512][128], KC=64, 8 chunks, ksplit
      const float4* g4 = (const float4*)(p.Wf + W2_OFF + l * 65536);
      const int st = w >> 1, hf = w & 1;
      const int slot = w * 256 + lane;
      float4 L0 = g4[slot], L1 = g4[slot + 64], L2 = g4[slot + 128], L3 = g4[slot + 192];
      float4 acc = {0,0,0,0};
      for (int c = 0; c < 8; ++c) {
        float4* bw = stage4 + (c & 1) * 2048;
        bw[slot] = L0; bw[slot + 64] = L1; bw[slot + 128] = L2; bw[slot + 192] = L3;
        if (c < 7) { int b = (c + 1) * 2048 + slot; L0 = g4[b]; L1 = g4[b + 64]; L2 = g4[b + 128]; L3 = g4[b + 192]; }
        asm volatile("s_waitcnt lgkmcnt(0)" ::: "memory");
        __builtin_amdgcn_s_barrier();
        const float* bc = stage + (c & 1) * 8192;
        float4 xf[8];
        #pragma unroll
        for (int j = 0; j < 8; ++j) xf[j] = *(const float4*)&f1s[r][c * 64 + hf * 32 + j * 4];
        #pragma unroll
        for (int kk = 0; kk < 32; ++kk) {
          float xk = f4_at(xf[kk >> 2], kk);
          float4 wv = *(const float4*)(bc + (hf * 32 + kk) * 128 + st * 32 + c4 * 4);
          FMA4(acc, xk, wv);
        }
        __builtin_amdgcn_s_barrier();
      }
      if (hf == 0) *(float4*)&cmb[((st * 8 + r) * 8 + c4) * 4] = acc;
      __syncthreads();
      if (hf == 1) {
        float4 part = *(const float4*)&cmb[((st * 8 + r) * 8 + c4) * 4];
        int col = st * 32 + c4 * 4;
        const float* bb = p.b2 + l * 128 + col;
        float4 xr = *(const float4*)&xs[r][col];
        tmp[r][col + 0] = acc.x + part.x + bb[0] + xr.x;
        tmp[r][col + 1] = acc.y + part.y + bb[1] + xr.y;
        tmp[r][col + 2] = acc.z + part.z + bb[2] + xr.z;
        tmp[r][col + 3] = acc.w + part.w + bb[3] + xr.w;
      }
      __syncthreads();
      lnorm(p.g2, p.be2, l);
      __syncthreads();
    }
  };

  qkv(0);
  grid.sync();  // sync 2: kv layer 0
  attn(0);
  oproj_ln(0);
  ffn(0);
  qkv(1);
  grid.sync();  // sync 3: kv layer 1
  attn(1);
  oproj_ln(1);
  ffn(1);

  // ---------------- final head: WT[128][1024], KC=8, 16 chunks, strips {w,w+8,w+16,w+24}
  {
    const float4* g4 = (const float4*)(p.Wf + WOUT_OFF);
    const int slot = w * 256 + lane;
    float4 L0 = g4[slot], L1 = g4[slot + 64], L2 = g4[slot + 128], L3 = g4[slot + 192];
    float4 a0 = {0,0,0,0}, a1 = {0,0,0,0}, a2 = {0,0,0,0}, a3 = {0,0,0,0};
    for (int c = 0; c < 16; ++c) {
      float4* bw = stage4 + (c & 1) * 2048;
      bw[slot] = L0; bw[slot + 64] = L1; bw[slot + 128] = L2; bw[slot + 192] = L3;
      if (c < 15) { int b = (c + 1) * 2048 + slot; L0 = g4[b]; L1 = g4[b + 64]; L2 = g4[b + 128]; L3 = g4[b + 192]; }
      asm volatile("s_waitcnt lgkmcnt(0)" ::: "memory");
      __builtin_amdgcn_s_barrier();
      const float* bc = stage + (c & 1) * 8192;
      float4 xf0 = *(const float4*)&xts[r][c * 8];
      float4 xf1 = *(const float4*)&xts[r][c * 8 + 4];
      #pragma unroll
      for (int kk = 0; kk < 8; ++kk) {
        float xk = (kk < 4) ? f4_at(xf0, kk) : f4_at(xf1, kk);
        const float* row = bc + kk * 1024 + c4 * 4;
        float4 m0 = *(const float4*)(row + (w +  0) * 32);
        float4 m1 = *(const float4*)(row + (w +  8) * 32);
        float4 m2 = *(const float4*)(row + (w + 16) * 32);
        float4 m3 = *(const float4*)(row + (w + 24) * 32);
        FMA4(a0, xk, m0); FMA4(a1, xk, m1); FMA4(a2, xk, m2); FMA4(a3, xk, m3);
      }
      __builtin_amdgcn_s_barrier();
    }
    size_t orow = (size_t)(batch * 128 + s0 + r) * 1024;
    #pragma unroll
    for (int m = 0; m < 4; ++m) {
      float4 a = (m == 0) ? a0 : (m == 1) ? a1 : (m == 2) ? a2 : a3;
      int col = (w + 8 * m) * 32 + c4 * 4;
      float4 o;
      o.x = a.x + p.bout[col + 0]; o.y = a.y + p.bout[col + 1];
      o.z = a.z + p.bout[col + 2]; o.w = a.w + p.bout[col + 3];
      *(float4*)(p.out + orow + col) = o;
    }
  }
}

extern "C" void kernel_launch(void* const* d_in, const int* in_sizes, int n_in,
                              void* d_out, int out_size, void* d_ws, size_t ws_size,
                              hipStream_t stream)
{
  Params p;
  p.tok  = (const int*)d_in[0];
  p.emb  = (const float*)d_in[1];
  p.pos  = (const float*)d_in[2];
  p.Wq   = (const float*)d_in[3];  p.bq  = (const float*)d_in[4];
  p.Wk   = (const float*)d_in[5];  p.bk  = (const float*)d_in[6];
  p.Wv   = (const float*)d_in[7];  p.bv  = (const float*)d_in[8];
  p.Wo   = (const float*)d_in[9];  p.bo  = (const float*)d_in[10];
  p.W1   = (const float*)d_in[11]; p.b1  = (const float*)d_in[12];
  p.W2   = (const float*)d_in[13]; p.b2  = (const float*)d_in[14];
  p.g1   = (const float*)d_in[15]; p.be1 = (const float*)d_in[16];
  p.g2   = (const float*)d_in[17]; p.be2 = (const float*)d_in[18];
  p.Wout = (const float*)d_in[19]; p.bout = (const float*)d_in[20];

  float* w = (float*)d_ws;
  p.Wf = w;                 // 524288 floats, transposed/merged
  p.kv = w + 524288;        // 131072 floats: [l][K/V][b][s][d]
  p.out = (float*)d_out;

  void* args[] = { (void*)&p };
  hipLaunchCooperativeKernel((const void*)k_model, dim3(NBLK), dim3(TPB),
                             args, 0, stream);
}

// Round 8
// 190.062 us; speedup vs baseline: 2.1568x; 1.2616x over previous
//
#include <hip/hip_runtime.h>

#define NBLK 32
#define TPB 512

// ws weight layout (floats), all k-major (transposed), QKV column-merged:
// WqkvT[l][128][384] | WoT[l][128][128] | W1T[l][128][512] | W2T[l][512][128] | WoutT[128][1024]
#define WQKV_OFF 0
#define WO_OFF   98304
#define W1_OFF   131072
#define W2_OFF   262144
#define WOUT_OFF 393216

#define INIT_MAGIC 0xC0FFEE01u

struct Params {
  const int* tok; const float* emb; const float* pos;
  const float* Wq; const float* bq; const float* Wk; const float* bk;
  const float* Wv; const float* bv; const float* Wo; const float* bo;
  const float* W1; const float* b1; const float* W2; const float* b2;
  const float* g1; const float* be1; const float* g2; const float* be2;
  const float* Wout; const float* bout;
  float* Wf; float* kv; unsigned* ctr; float* out;
};

// f(v) = rint(m*8)*2^(2e-3), v=m*2^e. Each l_mul term is exactly f(x)*f(w).
__device__ __forceinline__ float lmul_tf(float v) {
  int e; float m = frexpf(v, &e);
  return ldexpf(rintf(m * 8.0f), 2 * e - 3);
}
__device__ __forceinline__ float f4_at(const float4 v, int i) {
  switch (i & 3) { case 0: return v.x; case 1: return v.y; case 2: return v.z; default: return v.w; }
}
#define FMA4(acc, s, v) { acc.x += (s)*(v).x; acc.y += (s)*(v).y; acc.z += (s)*(v).z; acc.w += (s)*(v).w; }

// device-coherent (agent-scope) float4 store: visible at L3 without wbl2 fences
__device__ __forceinline__ void store_f4_agent(float* dst, float4 v) {
  unsigned long long u0, u1;
  __builtin_memcpy(&u0, &v, 8);
  __builtin_memcpy(&u1, reinterpret_cast<char*>(&v) + 8, 8);
  __hip_atomic_store(reinterpret_cast<unsigned long long*>(dst),     u0,
                     __ATOMIC_RELAXED, __HIP_MEMORY_SCOPE_AGENT);
  __hip_atomic_store(reinterpret_cast<unsigned long long*>(dst) + 1, u1,
                     __ATOMIC_RELAXED, __HIP_MEMORY_SCOPE_AGENT);
}

__global__ __launch_bounds__(512, 1) void k_model(Params p) {
  __shared__ __align__(16) float xs [8][132];
  __shared__ __align__(16) float xts[8][132];
  __shared__ __align__(16) float qs [8][132];
  __shared__ __align__(16) float atb[8][132];
  __shared__ __align__(16) float tmp[8][132];
  __shared__ __align__(16) float f1s[8][516];
  __shared__ __align__(16) float ps [8][4][129];
  __shared__ float4 stage4[4096];                  // 64 KB dbuf / scratch
  __shared__ __align__(16) float cmb[3072];        // k-split combine
  float* stage = (float*)stage4;

  const int bid = blockIdx.x, t = threadIdx.x;
  const int batch = bid >> 4, s0 = (bid & 15) * 8;
  const int lane = t & 63, w = t >> 6;
  const int c4 = lane & 7, r = lane >> 3;

  // ---------------- phase 0: transform + transpose weights (4 64x64 tiles/block); embed
  {
    for (int i = 0; i < 4; ++i) {
      int tid = bid * 4 + i;
      const float* src; float* dst; int srcK, dstC, cc0, kk0, dcol0;
      if (tid < 32) {
        int m = tid >> 3, rem = tid & 7, l = rem >> 2, ts = rem & 3;
        cc0 = (ts >> 1) * 64; kk0 = (ts & 1) * 64;
        src = (m == 0 ? p.Wq : m == 1 ? p.Wk : m == 2 ? p.Wv : p.Wo) + l * 16384;
        srcK = 128;
        if (m < 3) { dst = p.Wf + WQKV_OFF + l * 49152; dstC = 384; dcol0 = m * 128 + cc0; }
        else       { dst = p.Wf + WO_OFF   + l * 16384; dstC = 128; dcol0 = cc0; }
      } else if (tid < 64) {
        int rm = tid - 32, l = rm >> 4, ts = rm & 15;
        cc0 = (ts >> 1) * 64; kk0 = (ts & 1) * 64;
        src = p.W1 + l * 65536; dst = p.Wf + W1_OFF + l * 65536;
        srcK = 128; dstC = 512; dcol0 = cc0;
      } else if (tid < 96) {
        int rm = tid - 64, l = rm >> 4, ts = rm & 15;
        cc0 = (ts >> 3) * 64; kk0 = (ts & 7) * 64;
        src = p.W2 + l * 65536; dst = p.Wf + W2_OFF + l * 65536;
        srcK = 512; dstC = 128; dcol0 = cc0;
      } else {
        int rm = tid - 96, ts = rm & 31;
        cc0 = (ts >> 1) * 64; kk0 = (ts & 1) * 64;
        src = p.Wout; dst = p.Wf + WOUT_OFF;
        srcK = 128; dstC = 1024; dcol0 = cc0;
      }
      #pragma unroll
      for (int u = 0; u < 2; ++u) {
        int idx = t + u * 512, row = idx >> 4, col4 = idx & 15;
        float4 v = *(const float4*)(src + (size_t)(cc0 + row) * srcK + kk0 + col4 * 4);
        float* dl = &stage[row * 65 + col4 * 4];
        dl[0] = lmul_tf(v.x); dl[1] = lmul_tf(v.y); dl[2] = lmul_tf(v.z); dl[3] = lmul_tf(v.w);
      }
      __syncthreads();
      #pragma unroll
      for (int u = 0; u < 2; ++u) {
        int idx = t + u * 512, krow = idx >> 4, cc4 = idx & 15;
        float4 o;
        o.x = stage[(cc4 * 4 + 0) * 65 + krow];
        o.y = stage[(cc4 * 4 + 1) * 65 + krow];
        o.z = stage[(cc4 * 4 + 2) * 65 + krow];
        o.w = stage[(cc4 * 4 + 3) * 65 + krow];
        store_f4_agent(dst + (size_t)(kk0 + krow) * dstC + dcol0 + cc4 * 4, o);
      }
      __syncthreads();
    }
    for (int i = t; i < 8 * 128; i += TPB) {
      int rr = i >> 7, d = i & 127;
      float val = p.emb[p.tok[batch * 128 + s0 + rr] * 128 + d] + p.pos[(s0 + rr) * 128 + d];
      xs[rr][d] = val; xts[rr][d] = lmul_tf(val);
    }
  }
  // ---------------- weights-ready barrier (fence-free; replaces grid.sync 1)
  {
    if (bid == 0 && t == 0) {
      #pragma unroll
      for (int i = 0; i < 5; ++i)
        __hip_atomic_store(p.ctr + 64 * i, 0u, __ATOMIC_RELAXED, __HIP_MEMORY_SCOPE_AGENT);
      asm volatile("s_waitcnt vmcnt(0)" ::: "memory");
      __hip_atomic_store(p.ctr + 320, INIT_MAGIC, __ATOMIC_RELAXED, __HIP_MEMORY_SCOPE_AGENT);
    }
    asm volatile("s_waitcnt vmcnt(0)" ::: "memory");  // each wave: Wf stores retired
    __syncthreads();
    if (t == 0) {
      while (__hip_atomic_load(p.ctr + 320, __ATOMIC_RELAXED, __HIP_MEMORY_SCOPE_AGENT) != INIT_MAGIC)
        __builtin_amdgcn_s_sleep(1);
      __hip_atomic_fetch_add(p.ctr, 1u, __ATOMIC_RELAXED, __HIP_MEMORY_SCOPE_AGENT);
      while (__hip_atomic_load(p.ctr, __ATOMIC_RELAXED, __HIP_MEMORY_SCOPE_AGENT) < 32u)
        __builtin_amdgcn_s_sleep(1);
    }
    __syncthreads();
    asm volatile("" ::: "memory");
  }

  // per-batch KV-ready barrier (16 blocks), fence-free
  auto kv_barrier = [&](int l) {
    unsigned* c = p.ctr + 64 * (1 + l * 2 + batch);
    asm volatile("s_waitcnt vmcnt(0)" ::: "memory");
    __syncthreads();
    if (t == 0) {
      __hip_atomic_fetch_add(c, 1u, __ATOMIC_RELAXED, __HIP_MEMORY_SCOPE_AGENT);
      while (__hip_atomic_load(c, __ATOMIC_RELAXED, __HIP_MEMORY_SCOPE_AGENT) < 16u)
        __builtin_amdgcn_s_sleep(1);
    }
    __syncthreads();
    asm volatile("" ::: "memory");
  };

  // ---------------- QKV: WT[128][384], KC=16, 8 chunks, ksplit
  auto qkv = [&](int l) {
    const float4* g4 = (const float4*)(p.Wf + WQKV_OFF + l * 49152);
    const int sA = w >> 1, sB = sA + 4, sC = sA + 8, hf = w & 1;
    const int slot = w * 192 + lane;
    float4 L0 = g4[slot], L1 = g4[slot + 64], L2 = g4[slot + 128];
    float4 aA = {0,0,0,0}, aB = {0,0,0,0}, aC = {0,0,0,0};
    for (int c = 0; c < 8; ++c) {
      float4* bw = stage4 + (c & 1) * 1536;
      bw[slot] = L0; bw[slot + 64] = L1; bw[slot + 128] = L2;
      if (c < 7) { int b = (c + 1) * 1536 + slot; L0 = g4[b]; L1 = g4[b + 64]; L2 = g4[b + 128]; }
      asm volatile("s_waitcnt lgkmcnt(0)" ::: "memory");
      __builtin_amdgcn_s_barrier();
      const float* bc = stage + (c & 1) * 6144;
      float4 xf0 = *(const float4*)&xts[r][c * 16 + hf * 8];
      float4 xf1 = *(const float4*)&xts[r][c * 16 + hf * 8 + 4];
      #pragma unroll
      for (int kk = 0; kk < 8; ++kk) {
        float xk = (kk < 4) ? f4_at(xf0, kk) : f4_at(xf1, kk);
        const float* row = bc + (hf * 8 + kk) * 384 + c4 * 4;
        float4 wA = *(const float4*)(row + sA * 32);
        float4 wB = *(const float4*)(row + sB * 32);
        float4 wC = *(const float4*)(row + sC * 32);
        FMA4(aA, xk, wA); FMA4(aB, xk, wB); FMA4(aC, xk, wC);
      }
      __builtin_amdgcn_s_barrier();
    }
    if (hf == 0) {
      *(float4*)&cmb[((sA * 8 + r) * 8 + c4) * 4] = aA;
      *(float4*)&cmb[((sB * 8 + r) * 8 + c4) * 4] = aB;
      *(float4*)&cmb[((sC * 8 + r) * 8 + c4) * 4] = aC;
    }
    __syncthreads();
    if (hf == 1) {
      #pragma unroll
      for (int j = 0; j < 3; ++j) {
        int s = (j == 0) ? sA : (j == 1) ? sB : sC;
        float4 acc = (j == 0) ? aA : (j == 1) ? aB : aC;
        float4 part = *(const float4*)&cmb[((s * 8 + r) * 8 + c4) * 4];
        int proj = s >> 2, cip = (s & 3) * 32 + c4 * 4;
        const float* bb = (proj == 0 ? p.bq : proj == 1 ? p.bk : p.bv) + l * 128 + cip;
        acc.x += part.x + bb[0]; acc.y += part.y + bb[1];
        acc.z += part.z + bb[2]; acc.w += part.w + bb[3];
        if (proj == 0) *(float4*)&qs[r][cip] = acc;
        else store_f4_agent(p.kv + (size_t)((l * 2 + (proj - 1)) * 2 + batch) * 16384
                            + (s0 + r) * 128 + cip, acc);
      }
    }
    __syncthreads();
  };

  // ---------------- attention (K and V staged through LDS in 32-row chunks)
  auto attn = [&](int l) {
    const float* Kb = p.kv + (size_t)((l * 2 + 0) * 2 + batch) * 16384;
    const float* Vb = p.kv + (size_t)((l * 2 + 1) * 2 + batch) * 16384;
    int rq = t >> 6, h = (t >> 4) & 3, kc = t & 15;
    float4 qv[8];
    #pragma unroll
    for (int d4 = 0; d4 < 8; ++d4) qv[d4] = *(const float4*)&qs[rq][h * 32 + d4 * 4];
    float sc[8];
    for (int chunk = 0; chunk < 4; ++chunk) {
      #pragma unroll
      for (int u = 0; u < 2; ++u) {
        int idx = t + u * 512, row = idx >> 5, col4 = idx & 31;
        *(float4*)&stage[row * 132 + col4 * 4] =
            *(const float4*)(Kb + (chunk * 32 + row) * 128 + col4 * 4);
      }
      __syncthreads();
      #pragma unroll
      for (int m2 = 0; m2 < 2; ++m2) {
        int sl = kc + 16 * m2;
        float a = 0.f;
        #pragma unroll
        for (int d4 = 0; d4 < 8; ++d4) {
          float4 k4 = *(const float4*)&stage[sl * 132 + h * 32 + d4 * 4];
          a += qv[d4].x * k4.x + qv[d4].y * k4.y + qv[d4].z * k4.z + qv[d4].w * k4.w;
        }
        sc[chunk * 2 + m2] = a * 0.17677669529663687f;
      }
      __syncthreads();
    }
    float mx = -1e30f;
    #pragma unroll
    for (int m = 0; m < 8; ++m) mx = fmaxf(mx, sc[m]);
    #pragma unroll
    for (int off = 1; off < 16; off <<= 1) mx = fmaxf(mx, __shfl_xor(mx, off));
    float sum = 0.f;
    #pragma unroll
    for (int m = 0; m < 8; ++m) { sc[m] = expf(sc[m] - mx); sum += sc[m]; }
    #pragma unroll
    for (int off = 1; off < 16; off <<= 1) sum += __shfl_xor(sum, off);
    float inv = 1.f / sum;
    #pragma unroll
    for (int m = 0; m < 8; ++m) ps[rq][h][kc + 16 * m] = sc[m] * inv;
    __syncthreads();
    // PV with V staged
    int r2 = t & 7, d0 = (t >> 3) * 2, hh = d0 >> 5;
    float a0 = 0.f, a1 = 0.f;
    for (int ch = 0; ch < 4; ++ch) {
      #pragma unroll
      for (int u = 0; u < 2; ++u) {
        int idx = t + u * 512, row = idx >> 5, col4 = idx & 31;
        *(float4*)&stage[row * 132 + col4 * 4] =
            *(const float4*)(Vb + (ch * 32 + row) * 128 + col4 * 4);
      }
      __syncthreads();
      #pragma unroll
      for (int ss = 0; ss < 32; ++ss) {
        float pp = ps[r2][hh][ch * 32 + ss];
        a0 += pp * stage[ss * 132 + d0];
        a1 += pp * stage[ss * 132 + d0 + 1];
      }
      __syncthreads();
    }
    atb[r2][d0] = lmul_tf(a0); atb[r2][d0 + 1] = lmul_tf(a1);
    __syncthreads();
  };

  auto lnorm = [&](const float* g, const float* be, int l) {
    int rw = t >> 6, li = t & 63;
    float v0 = tmp[rw][li], v1 = tmp[rw][li + 64];
    float s = v0 + v1, s2 = v0 * v0 + v1 * v1;
    #pragma unroll
    for (int off = 1; off < 64; off <<= 1) { s += __shfl_xor(s, off); s2 += __shfl_xor(s2, off); }
    float mu = s * (1.f / 128.f);
    float var = s2 * (1.f / 128.f) - mu * mu;
    float rr2 = rsqrtf(var + 1e-5f);
    float n0 = (v0 - mu) * rr2 * g[l * 128 + li]      + be[l * 128 + li];
    float n1 = (v1 - mu) * rr2 * g[l * 128 + li + 64] + be[l * 128 + li + 64];
    xs[rw][li] = n0;           xs[rw][li + 64] = n1;
    xts[rw][li] = lmul_tf(n0); xts[rw][li + 64] = lmul_tf(n1);
  };

  // ---------------- O-proj + LN: WT[128][128], KC=64, 2 chunks, ksplit
  auto oproj_ln = [&](int l) {
    const float4* g4 = (const float4*)(p.Wf + WO_OFF + l * 16384);
    const int st = w >> 1, hf = w & 1;
    const int slot = w * 256 + lane;
    float4 L0 = g4[slot], L1 = g4[slot + 64], L2 = g4[slot + 128], L3 = g4[slot + 192];
    float4 acc = {0,0,0,0};
    for (int c = 0; c < 2; ++c) {
      float4* bw = stage4 + (c & 1) * 2048;
      bw[slot] = L0; bw[slot + 64] = L1; bw[slot + 128] = L2; bw[slot + 192] = L3;
      if (c < 1) { int b = 2048 + slot; L0 = g4[b]; L1 = g4[b + 64]; L2 = g4[b + 128]; L3 = g4[b + 192]; }
      asm volatile("s_waitcnt lgkmcnt(0)" ::: "memory");
      __builtin_amdgcn_s_barrier();
      const float* bc = stage + (c & 1) * 8192;
      float4 xf[8];
      #pragma unroll
      for (int j = 0; j < 8; ++j) xf[j] = *(const float4*)&atb[r][c * 64 + hf * 32 + j * 4];
      #pragma unroll
      for (int kk = 0; kk < 32; ++kk) {
        float xk = f4_at(xf[kk >> 2], kk);
        float4 wv = *(const float4*)(bc + (hf * 32 + kk) * 128 + st * 32 + c4 * 4);
        FMA4(acc, xk, wv);
      }
      __builtin_amdgcn_s_barrier();
    }
    if (hf == 0) *(float4*)&cmb[((st * 8 + r) * 8 + c4) * 4] = acc;
    __syncthreads();
    if (hf == 1) {
      float4 part = *(const float4*)&cmb[((st * 8 + r) * 8 + c4) * 4];
      int col = st * 32 + c4 * 4;
      const float* bb = p.bo + l * 128 + col;
      float4 xr = *(const float4*)&xs[r][col];
      tmp[r][col + 0] = acc.x + part.x + bb[0] + xr.x;
      tmp[r][col + 1] = acc.y + part.y + bb[1] + xr.y;
      tmp[r][col + 2] = acc.z + part.z + bb[2] + xr.z;
      tmp[r][col + 3] = acc.w + part.w + bb[3] + xr.w;
    }
    __syncthreads();
    lnorm(p.g1, p.be1, l);
    __syncthreads();
  };

  // ---------------- FFN
  auto ffn = [&](int l) {
    { // FF1: WT[128][512], KC=16, 8 chunks, strips {w, w+8}
      const float4* g4 = (const float4*)(p.Wf + W1_OFF + l * 65536);
      const int slot = w * 256 + lane;
      float4 L0 = g4[slot], L1 = g4[slot + 64], L2 = g4[slot + 128], L3 = g4[slot + 192];
      float4 aA = {0,0,0,0}, aB = {0,0,0,0};
      for (int c = 0; c < 8; ++c) {
        float4* bw = stage4 + (c & 1) * 2048;
        bw[slot] = L0; bw[slot + 64] = L1; bw[slot + 128] = L2; bw[slot + 192] = L3;
        if (c < 7) { int b = (c + 1) * 2048 + slot; L0 = g4[b]; L1 = g4[b + 64]; L2 = g4[b + 128]; L3 = g4[b + 192]; }
        asm volatile("s_waitcnt lgkmcnt(0)" ::: "memory");
        __builtin_amdgcn_s_barrier();
        const float* bc = stage + (c & 1) * 8192;
        float4 xf[4];
        #pragma unroll
        for (int j = 0; j < 4; ++j) xf[j] = *(const float4*)&xts[r][c * 16 + j * 4];
        #pragma unroll
        for (int kk = 0; kk < 16; ++kk) {
          float xk = f4_at(xf[kk >> 2], kk);
          const float* row = bc + kk * 512 + c4 * 4;
          float4 wA = *(const float4*)(row + w * 32);
          float4 wB = *(const float4*)(row + (w + 8) * 32);
          FMA4(aA, xk, wA); FMA4(aB, xk, wB);
        }
        __builtin_amdgcn_s_barrier();
      }
      const float* b1p = p.b1 + l * 512;
      int colA = w * 32 + c4 * 4, colB = (w + 8) * 32 + c4 * 4;
      float4 oA, oB;
      oA.x = lmul_tf(fmaxf(aA.x + b1p[colA + 0], 0.f));
      oA.y = lmul_tf(fmaxf(aA.y + b1p[colA + 1], 0.f));
      oA.z = lmul_tf(fmaxf(aA.z + b1p[colA + 2], 0.f));
      oA.w = lmul_tf(fmaxf(aA.w + b1p[colA + 3], 0.f));
      oB.x = lmul_tf(fmaxf(aB.x + b1p[colB + 0], 0.f));
      oB.y = lmul_tf(fmaxf(aB.y + b1p[colB + 1], 0.f));
      oB.z = lmul_tf(fmaxf(aB.z + b1p[colB + 2], 0.f));
      oB.w = lmul_tf(fmaxf(aB.w + b1p[colB + 3], 0.f));
      *(float4*)&f1s[r][colA] = oA;
      *(float4*)&f1s[r][colB] = oB;
    }
    __syncthreads();
    { // FF2: WT[512][128], KC=64, 8 chunks, ksplit
      const float4* g4 = (const float4*)(p.Wf + W2_OFF + l * 65536);
      const int st = w >> 1, hf = w & 1;
      const int slot = w * 256 + lane;
      float4 L0 = g4[slot], L1 = g4[slot + 64], L2 = g4[slot + 128], L3 = g4[slot + 192];
      float4 acc = {0,0,0,0};
      for (int c = 0; c < 8; ++c) {
        float4* bw = stage4 + (c & 1) * 2048;
        bw[slot] = L0; bw[slot + 64] = L1; bw[slot + 128] = L2; bw[slot + 192] = L3;
        if (c < 7) { int b = (c + 1) * 2048 + slot; L0 = g4[b]; L1 = g4[b + 64]; L2 = g4[b + 128]; L3 = g4[b + 192]; }
        asm volatile("s_waitcnt lgkmcnt(0)" ::: "memory");
        __builtin_amdgcn_s_barrier();
        const float* bc = stage + (c & 1) * 8192;
        float4 xf[8];
        #pragma unroll
        for (int j = 0; j < 8; ++j) xf[j] = *(const float4*)&f1s[r][c * 64 + hf * 32 + j * 4];
        #pragma unroll
        for (int kk = 0; kk < 32; ++kk) {
          float xk = f4_at(xf[kk >> 2], kk);
          float4 wv = *(const float4*)(bc + (hf * 32 + kk) * 128 + st * 32 + c4 * 4);
          FMA4(acc, xk, wv);
        }
        __builtin_amdgcn_s_barrier();
      }
      if (hf == 0) *(float4*)&cmb[((st * 8 + r) * 8 + c4) * 4] = acc;
      __syncthreads();
      if (hf == 1) {
        float4 part = *(const float4*)&cmb[((st * 8 + r) * 8 + c4) * 4];
        int col = st * 32 + c4 * 4;
        const float* bb = p.b2 + l * 128 + col;
        float4 xr = *(const float4*)&xs[r][col];
        tmp[r][col + 0] = acc.x + part.x + bb[0] + xr.x;
        tmp[r][col + 1] = acc.y + part.y + bb[1] + xr.y;
        tmp[r][col + 2] = acc.z + part.z + bb[2] + xr.z;
        tmp[r][col + 3] = acc.w + part.w + bb[3] + xr.w;
      }
      __syncthreads();
      lnorm(p.g2, p.be2, l);
      __syncthreads();
    }
  };

  qkv(0);
  kv_barrier(0);
  attn(0);
  oproj_ln(0);
  ffn(0);
  qkv(1);
  kv_barrier(1);
  attn(1);
  oproj_ln(1);
  ffn(1);

  // ---------------- final head: WT[128][1024], KC=8, 16 chunks
  {
    const float4* g4 = (const float4*)(p.Wf + WOUT_OFF);
    const int slot = w * 256 + lane;
    float4 L0 = g4[slot], L1 = g4[slot + 64], L2 = g4[slot + 128], L3 = g4[slot + 192];
    float4 a0 = {0,0,0,0}, a1 = {0,0,0,0}, a2 = {0,0,0,0}, a3 = {0,0,0,0};
    for (int c = 0; c < 16; ++c) {
      float4* bw = stage4 + (c & 1) * 2048;
      bw[slot] = L0; bw[slot + 64] = L1; bw[slot + 128] = L2; bw[slot + 192] = L3;
      if (c < 15) { int b = (c + 1) * 2048 + slot; L0 = g4[b]; L1 = g4[b + 64]; L2 = g4[b + 128]; L3 = g4[b + 192]; }
      asm volatile("s_waitcnt lgkmcnt(0)" ::: "memory");
      __builtin_amdgcn_s_barrier();
      const float* bc = stage + (c & 1) * 8192;
      float4 xf0 = *(const float4*)&xts[r][c * 8];
      float4 xf1 = *(const float4*)&xts[r][c * 8 + 4];
      #pragma unroll
      for (int kk = 0; kk < 8; ++kk) {
        float xk = (kk < 4) ? f4_at(xf0, kk) : f4_at(xf1, kk);
        const float* row = bc + kk * 1024 + c4 * 4;
        float4 m0 = *(const float4*)(row + (w +  0) * 32);
        float4 m1 = *(const float4*)(row + (w +  8) * 32);
        float4 m2 = *(const float4*)(row + (w + 16) * 32);
        float4 m3 = *(const float4*)(row + (w + 24) * 32);
        FMA4(a0, xk, m0); FMA4(a1, xk, m1); FMA4(a2, xk, m2); FMA4(a3, xk, m3);
      }
      __builtin_amdgcn_s_barrier();
    }
    size_t orow = (size_t)(batch * 128 + s0 + r) * 1024;
    #pragma unroll
    for (int m = 0; m < 4; ++m) {
      float4 a = (m == 0) ? a0 : (m == 1) ? a1 : (m == 2) ? a2 : a3;
      int col = (w + 8 * m) * 32 + c4 * 4;
      float4 o;
      o.x = a.x + p.bout[col + 0]; o.y = a.y + p.bout[col + 1];
      o.z = a.z + p.bout[col + 2]; o.w = a.w + p.bout[col + 3];
      *(float4*)(p.out + orow + col) = o;
    }
  }
}

extern "C" void kernel_launch(void* const* d_in, const int* in_sizes, int n_in,
                              void* d_out, int out_size, void* d_ws, size_t ws_size,
                              hipStream_t stream)
{
  Params p;
  p.tok  = (const int*)d_in[0];
  p.emb  = (const float*)d_in[1];
  p.pos  = (const float*)d_in[2];
  p.Wq   = (const float*)d_in[3];  p.bq  = (const float*)d_in[4];
  p.Wk   = (const float*)d_in[5];  p.bk  = (const float*)d_in[6];
  p.Wv   = (const float*)d_in[7];  p.bv  = (const float*)d_in[8];
  p.Wo   = (const float*)d_in[9];  p.bo  = (const float*)d_in[10];
  p.W1   = (const float*)d_in[11]; p.b1  = (const float*)d_in[12];
  p.W2   = (const float*)d_in[13]; p.b2  = (const float*)d_in[14];
  p.g1   = (const float*)d_in[15]; p.be1 = (const float*)d_in[16];
  p.g2   = (const float*)d_in[17]; p.be2 = (const float*)d_in[18];
  p.Wout = (const float*)d_in[19]; p.bout = (const float*)d_in[20];

  float* w = (float*)d_ws;
  p.Wf  = w;                              // 524288 floats, transposed/merged
  p.kv  = w + 524288;                     // 131072 floats: [l][K/V][b][s][d]
  p.ctr = (unsigned*)(w + 524288 + 131072); // flag counters (init-gated)
  p.out = (float*)d_out;

  k_model<<<dim3(NBLK), dim3(TPB), 0, stream>>>(p);
}

// Round 9
// 150.719 us; speedup vs baseline: 2.7199x; 1.2610x over previous
//
#include <hip/hip_runtime.h>

#define NBLK 32
#define TPB 512

typedef __attribute__((ext_vector_type(8))) short short8v;
typedef __attribute__((ext_vector_type(4))) float f32x4;
typedef unsigned short ushort;

// Wf (bf16/ushort units), each matrix pre-tiled in MFMA B-frag order:
// idx = (((l*NT + nt)*KT + kt)*64 + lane)*8 + j ;  elem = W[n][k],
// n = nt*16 + (lane&15), k = kt*32 + (lane>>4)*8 + j
#define WT_Q   0
#define WT_K   32768
#define WT_V   65536
#define WT_O   98304
#define WT_1   131072
#define WT_2   262144
#define WT_OUT 393216

#define INIT_MAGIC 0xC0FFEE01u

struct Params {
  const int* tok; const float* emb; const float* pos;
  const float* Wq; const float* bq; const float* Wk; const float* bk;
  const float* Wv; const float* bv; const float* Wo; const float* bo;
  const float* W1; const float* b1; const float* W2; const float* b2;
  const float* g1; const float* be1; const float* g2; const float* be2;
  const float* Wout; const float* bout;
  ushort* Wf; float* kv; unsigned* ctr; float* out;
};

// f(v) = rint(m*8)*2^(2e-3): <=4-bit mantissa -> exact in bf16.
__device__ __forceinline__ float lmul_tf(float v) {
  int e; float m = frexpf(v, &e);
  return ldexpf(rintf(m * 8.0f), 2 * e - 3);
}
__device__ __forceinline__ ushort bf16t(float v) {
  unsigned u; __builtin_memcpy(&u, &v, 4); return (ushort)(u >> 16);
}
__device__ __forceinline__ void store_f32_agent(float* dst, float v) {
  unsigned u; __builtin_memcpy(&u, &v, 4);
  __hip_atomic_store((unsigned*)dst, u, __ATOMIC_RELAXED, __HIP_MEMORY_SCOPE_AGENT);
}
__device__ __forceinline__ void store_u64_agent(unsigned long long* dst, unsigned long long v) {
  __hip_atomic_store(dst, v, __ATOMIC_RELAXED, __HIP_MEMORY_SCOPE_AGENT);
}

__global__ __launch_bounds__(512, 1) void k_model(Params p) {
  __shared__ __align__(16) float xs [8][132];      // raw x rows
  __shared__ __align__(16) float qs [8][132];      // Q rows fp32
  __shared__ __align__(16) float tmp[8][132];      // pre-LN
  __shared__ __align__(16) float ps [8][4][129];   // probs
  __shared__ __align__(16) float kscr[32][132];    // K/V staging
  __shared__ __align__(16) ushort xbf [16*128];    // bf16 f(x), rows 8-15 zero
  __shared__ __align__(16) ushort atbf[16*128];    // bf16 f(attn), rows 8-15 zero
  __shared__ __align__(16) ushort f1bf[16*512];    // bf16 f(relu(ff1)), rows 8-15 zero

  const int bid = blockIdx.x, t = threadIdx.x;
  const int batch = bid >> 4, s0 = (bid & 15) * 8;
  const int lane = t & 63, w = t >> 6;

  // ---------------- phase 0: transform weights -> bf16 tiled frags (grid-split); embed
  {
    int tid = bid * TPB + t;
    #pragma unroll
    for (int it = 0; it < 4; ++it) {
      int chunk = tid + it * 16384;            // 65536 chunks of 8 elems
      int e = chunk * 8;
      const float* src; int dstbase, K, rem, pls, ktb;
      if (e < 131072) {
        int m = e >> 15;
        src = (m == 0 ? p.Wq : m == 1 ? p.Wk : m == 2 ? p.Wv : p.Wo);
        dstbase = m * 32768; K = 128; rem = e & 32767; pls = 14; ktb = 2;
      } else if (e < 262144) {
        src = p.W1; dstbase = WT_1; K = 128; rem = e - 131072; pls = 16; ktb = 2;
      } else if (e < 393216) {
        src = p.W2; dstbase = WT_2; K = 512; rem = e - 262144; pls = 16; ktb = 4;
      } else {
        src = p.Wout; dstbase = WT_OUT; K = 128; rem = e - 393216; pls = 17; ktb = 2;
      }
      int l = rem >> pls, r2 = rem & ((1 << pls) - 1);
      int fragl = r2 >> 3;
      int lane_id = fragl & 63, ftile = fragl >> 6;
      int kt = ftile & ((1 << ktb) - 1), nt = ftile >> ktb;
      int n = nt * 16 + (lane_id & 15);
      int k0 = kt * 32 + (lane_id >> 4) * 8;
      const float* sp = src + ((size_t)l << pls) + (size_t)n * K + k0;
      float4 v0 = *(const float4*)sp, v1 = *(const float4*)(sp + 4);
      unsigned u0 = bf16t(lmul_tf(v0.x)) | ((unsigned)bf16t(lmul_tf(v0.y)) << 16);
      unsigned u1 = bf16t(lmul_tf(v0.z)) | ((unsigned)bf16t(lmul_tf(v0.w)) << 16);
      unsigned u2 = bf16t(lmul_tf(v1.x)) | ((unsigned)bf16t(lmul_tf(v1.y)) << 16);
      unsigned u3 = bf16t(lmul_tf(v1.z)) | ((unsigned)bf16t(lmul_tf(v1.w)) << 16);
      unsigned long long* dp = (unsigned long long*)(p.Wf + dstbase + rem);
      store_u64_agent(dp,     (unsigned long long)u0 | ((unsigned long long)u1 << 32));
      store_u64_agent(dp + 1, (unsigned long long)u2 | ((unsigned long long)u3 << 32));
    }
    for (int i = t; i < 8 * 128; i += TPB) {
      int rr = i >> 7, d = i & 127;
      float val = p.emb[p.tok[batch * 128 + s0 + rr] * 128 + d] + p.pos[(s0 + rr) * 128 + d];
      xs[rr][d] = val; xbf[rr * 128 + d] = bf16t(lmul_tf(val));
    }
    for (int i = t; i < 512; i += TPB) { ((unsigned*)xbf)[512 + i] = 0; ((unsigned*)atbf)[512 + i] = 0; }
    for (int i = t; i < 2048; i += TPB) ((unsigned*)f1bf)[2048 + i] = 0;
  }
  // ---------------- weights-ready barrier (fence-free)
  {
    if (bid == 0 && t == 0) {
      #pragma unroll
      for (int i = 0; i < 5; ++i)
        __hip_atomic_store(p.ctr + 64 * i, 0u, __ATOMIC_RELAXED, __HIP_MEMORY_SCOPE_AGENT);
      asm volatile("s_waitcnt vmcnt(0)" ::: "memory");
      __hip_atomic_store(p.ctr + 320, INIT_MAGIC, __ATOMIC_RELAXED, __HIP_MEMORY_SCOPE_AGENT);
    }
    asm volatile("s_waitcnt vmcnt(0)" ::: "memory");
    __syncthreads();
    if (t == 0) {
      while (__hip_atomic_load(p.ctr + 320, __ATOMIC_RELAXED, __HIP_MEMORY_SCOPE_AGENT) != INIT_MAGIC)
        __builtin_amdgcn_s_sleep(1);
      __hip_atomic_fetch_add(p.ctr, 1u, __ATOMIC_RELAXED, __HIP_MEMORY_SCOPE_AGENT);
      while (__hip_atomic_load(p.ctr, __ATOMIC_RELAXED, __HIP_MEMORY_SCOPE_AGENT) < 32u)
        __builtin_amdgcn_s_sleep(1);
    }
    __syncthreads();
    asm volatile("" ::: "memory");
  }

  auto kv_barrier = [&](int l) {
    unsigned* c = p.ctr + 64 * (1 + l * 2 + batch);
    asm volatile("s_waitcnt vmcnt(0)" ::: "memory");
    __syncthreads();
    if (t == 0) {
      __hip_atomic_fetch_add(c, 1u, __ATOMIC_RELAXED, __HIP_MEMORY_SCOPE_AGENT);
      while (__hip_atomic_load(c, __ATOMIC_RELAXED, __HIP_MEMORY_SCOPE_AGENT) < 16u)
        __builtin_amdgcn_s_sleep(1);
    }
    __syncthreads();
    asm volatile("" ::: "memory");
  };

  // A-frag: m = lane&15, k = kt*32 + (lane>>4)*8 + j
  auto ldA = [&](const ushort* Ab, int stride, int kt) -> short8v {
    return *(const short8v*)(Ab + (lane & 15) * stride + kt * 32 + ((lane >> 4) & 3) * 8);
  };

  // ---------------- QKV via MFMA: 24 n-tiles, 3 per wave
  auto qkv = [&](int l) {
    short8v A0 = ldA(xbf, 128, 0), A1 = ldA(xbf, 128, 1),
            A2 = ldA(xbf, 128, 2), A3 = ldA(xbf, 128, 3);
    #pragma unroll
    for (int i = 0; i < 3; ++i) {
      int tile = w + 8 * i;
      int proj = tile >> 3, nt = tile & 7;
      const short8v* Bp = (const short8v*)(p.Wf + (proj == 0 ? WT_Q : proj == 1 ? WT_K : WT_V))
                          + (size_t)((l * 8 + nt) * 4) * 64 + lane;
      short8v b0 = Bp[0], b1 = Bp[64], b2 = Bp[128], b3 = Bp[192];
      f32x4 acc = {0.f, 0.f, 0.f, 0.f};
      acc = __builtin_amdgcn_mfma_f32_16x16x32_bf16(A0, b0, acc, 0, 0, 0);
      acc = __builtin_amdgcn_mfma_f32_16x16x32_bf16(A1, b1, acc, 0, 0, 0);
      acc = __builtin_amdgcn_mfma_f32_16x16x32_bf16(A2, b2, acc, 0, 0, 0);
      acc = __builtin_amdgcn_mfma_f32_16x16x32_bf16(A3, b3, acc, 0, 0, 0);
      if (lane < 32) {
        int col = tile * 16 + (lane & 15);
        int rbase = (lane >> 4) * 4;
        if (proj == 0) {
          float bv = p.bq[l * 128 + col];
          #pragma unroll
          for (int j = 0; j < 4; ++j) qs[rbase + j][col] = acc[j] + bv;
        } else {
          int d = col & 127;
          float bv = (proj == 1 ? p.bk : p.bv)[l * 128 + d];
          float* dst = p.kv + (size_t)((l * 2 + (proj - 1)) * 2 + batch) * 16384 + d;
          #pragma unroll
          for (int j = 0; j < 4; ++j)
            store_f32_agent(dst + (size_t)(s0 + rbase + j) * 128, acc[j] + bv);
        }
      }
    }
    __syncthreads();
  };

  // ---------------- attention: fp32, unchanged structure (K/V via LDS chunks)
  auto attn = [&](int l) {
    const float* Kb = p.kv + (size_t)((l * 2 + 0) * 2 + batch) * 16384;
    const float* Vb = p.kv + (size_t)((l * 2 + 1) * 2 + batch) * 16384;
    int rq = t >> 6, h = (t >> 4) & 3, kc = t & 15;
    float4 qv[8];
    #pragma unroll
    for (int d4 = 0; d4 < 8; ++d4) qv[d4] = *(const float4*)&qs[rq][h * 32 + d4 * 4];
    float sc[8];
    for (int chunk = 0; chunk < 4; ++chunk) {
      #pragma unroll
      for (int u = 0; u < 2; ++u) {
        int idx = t + u * 512, row = idx >> 5, col4 = idx & 31;
        *(float4*)&kscr[row][col4 * 4] =
            *(const float4*)(Kb + (chunk * 32 + row) * 128 + col4 * 4);
      }
      __syncthreads();
      #pragma unroll
      for (int m2 = 0; m2 < 2; ++m2) {
        int sl = kc + 16 * m2;
        float a = 0.f;
        #pragma unroll
        for (int d4 = 0; d4 < 8; ++d4) {
          float4 k4 = *(const float4*)&kscr[sl][h * 32 + d4 * 4];
          a += qv[d4].x * k4.x + qv[d4].y * k4.y + qv[d4].z * k4.z + qv[d4].w * k4.w;
        }
        sc[chunk * 2 + m2] = a * 0.17677669529663687f;
      }
      __syncthreads();
    }
    float mx = -1e30f;
    #pragma unroll
    for (int m = 0; m < 8; ++m) mx = fmaxf(mx, sc[m]);
    #pragma unroll
    for (int off = 1; off < 16; off <<= 1) mx = fmaxf(mx, __shfl_xor(mx, off));
    float sum = 0.f;
    #pragma unroll
    for (int m = 0; m < 8; ++m) { sc[m] = expf(sc[m] - mx); sum += sc[m]; }
    #pragma unroll
    for (int off = 1; off < 16; off <<= 1) sum += __shfl_xor(sum, off);
    float inv = 1.f / sum;
    #pragma unroll
    for (int m = 0; m < 8; ++m) ps[rq][h][kc + 16 * m] = sc[m] * inv;
    __syncthreads();
    int r2 = t & 7, d0 = (t >> 3) * 2, hh = d0 >> 5;
    float a0 = 0.f, a1 = 0.f;
    for (int ch = 0; ch < 4; ++ch) {
      #pragma unroll
      for (int u = 0; u < 2; ++u) {
        int idx = t + u * 512, row = idx >> 5, col4 = idx & 31;
        *(float4*)&kscr[row][col4 * 4] =
            *(const float4*)(Vb + (ch * 32 + row) * 128 + col4 * 4);
      }
      __syncthreads();
      #pragma unroll
      for (int ss = 0; ss < 32; ++ss) {
        float pp = ps[r2][hh][ch * 32 + ss];
        a0 += pp * kscr[ss][d0];
        a1 += pp * kscr[ss][d0 + 1];
      }
      __syncthreads();
    }
    atbf[r2 * 128 + d0]     = bf16t(lmul_tf(a0));
    atbf[r2 * 128 + d0 + 1] = bf16t(lmul_tf(a1));
    __syncthreads();
  };

  auto lnorm = [&](const float* g, const float* be, int l) {
    int rw = t >> 6, li = t & 63;
    float v0 = tmp[rw][li], v1 = tmp[rw][li + 64];
    float s = v0 + v1, s2 = v0 * v0 + v1 * v1;
    #pragma unroll
    for (int off = 1; off < 64; off <<= 1) { s += __shfl_xor(s, off); s2 += __shfl_xor(s2, off); }
    float mu = s * (1.f / 128.f);
    float var = s2 * (1.f / 128.f) - mu * mu;
    float rr2 = rsqrtf(var + 1e-5f);
    float n0 = (v0 - mu) * rr2 * g[l * 128 + li]      + be[l * 128 + li];
    float n1 = (v1 - mu) * rr2 * g[l * 128 + li + 64] + be[l * 128 + li + 64];
    xs[rw][li] = n0;       xs[rw][li + 64] = n1;
    xbf[rw * 128 + li]      = bf16t(lmul_tf(n0));
    xbf[rw * 128 + li + 64] = bf16t(lmul_tf(n1));
  };

  // ---------------- O-proj + LN: 8 n-tiles, 1 per wave
  auto oproj_ln = [&](int l) {
    short8v A0 = ldA(atbf, 128, 0), A1 = ldA(atbf, 128, 1),
            A2 = ldA(atbf, 128, 2), A3 = ldA(atbf, 128, 3);
    const short8v* Bp = (const short8v*)(p.Wf + WT_O) + (size_t)((l * 8 + w) * 4) * 64 + lane;
    short8v b0 = Bp[0], b1 = Bp[64], b2 = Bp[128], b3 = Bp[192];
    f32x4 acc = {0.f, 0.f, 0.f, 0.f};
    acc = __builtin_amdgcn_mfma_f32_16x16x32_bf16(A0, b0, acc, 0, 0, 0);
    acc = __builtin_amdgcn_mfma_f32_16x16x32_bf16(A1, b1, acc, 0, 0, 0);
    acc = __builtin_amdgcn_mfma_f32_16x16x32_bf16(A2, b2, acc, 0, 0, 0);
    acc = __builtin_amdgcn_mfma_f32_16x16x32_bf16(A3, b3, acc, 0, 0, 0);
    if (lane < 32) {
      int col = w * 16 + (lane & 15);
      float bv = p.bo[l * 128 + col];
      int rbase = (lane >> 4) * 4;
      #pragma unroll
      for (int j = 0; j < 4; ++j)
        tmp[rbase + j][col] = acc[j] + bv + xs[rbase + j][col];
    }
    __syncthreads();
    lnorm(p.g1, p.be1, l);
    __syncthreads();
  };

  // ---------------- FFN
  auto ffn = [&](int l) {
    { // FF1: 32 n-tiles, 4 per wave
      short8v A0 = ldA(xbf, 128, 0), A1 = ldA(xbf, 128, 1),
              A2 = ldA(xbf, 128, 2), A3 = ldA(xbf, 128, 3);
      #pragma unroll
      for (int i = 0; i < 4; ++i) {
        int tile = w + 8 * i;
        const short8v* Bp = (const short8v*)(p.Wf + WT_1) + (size_t)((l * 32 + tile) * 4) * 64 + lane;
        short8v b0 = Bp[0], b1 = Bp[64], b2 = Bp[128], b3 = Bp[192];
        f32x4 acc = {0.f, 0.f, 0.f, 0.f};
        acc = __builtin_amdgcn_mfma_f32_16x16x32_bf16(A0, b0, acc, 0, 0, 0);
        acc = __builtin_amdgcn_mfma_f32_16x16x32_bf16(A1, b1, acc, 0, 0, 0);
        acc = __builtin_amdgcn_mfma_f32_16x16x32_bf16(A2, b2, acc, 0, 0, 0);
        acc = __builtin_amdgcn_mfma_f32_16x16x32_bf16(A3, b3, acc, 0, 0, 0);
        if (lane < 32) {
          int col = tile * 16 + (lane & 15);
          float bv = p.b1[l * 512 + col];
          int rbase = (lane >> 4) * 4;
          #pragma unroll
          for (int j = 0; j < 4; ++j)
            f1bf[(rbase + j) * 512 + col] = bf16t(lmul_tf(fmaxf(acc[j] + bv, 0.f)));
        }
      }
    }
    __syncthreads();
    { // FF2: K=512 -> 16 k-tiles; 8 n-tiles, 1 per wave
      const short8v* Bp = (const short8v*)(p.Wf + WT_2) + (size_t)((l * 8 + w) * 16) * 64 + lane;
      short8v Bf[16];
      #pragma unroll
      for (int kt = 0; kt < 16; ++kt) Bf[kt] = Bp[(size_t)kt * 64];
      f32x4 acc = {0.f, 0.f, 0.f, 0.f};
      #pragma unroll
      for (int kt = 0; kt < 16; ++kt) {
        short8v a = *(const short8v*)(f1bf + (lane & 15) * 512 + kt * 32 + ((lane >> 4) & 3) * 8);
        acc = __builtin_amdgcn_mfma_f32_16x16x32_bf16(a, Bf[kt], acc, 0, 0, 0);
      }
      if (lane < 32) {
        int col = w * 16 + (lane & 15);
        float bv = p.b2[l * 128 + col];
        int rbase = (lane >> 4) * 4;
        #pragma unroll
        for (int j = 0; j < 4; ++j)
          tmp[rbase + j][col] = acc[j] + bv + xs[rbase + j][col];
      }
      __syncthreads();
      lnorm(p.g2, p.be2, l);
      __syncthreads();
    }
  };

  qkv(0);
  kv_barrier(0);
  attn(0);
  oproj_ln(0);
  ffn(0);
  qkv(1);
  kv_barrier(1);
  attn(1);
  oproj_ln(1);
  ffn(1);

  // ---------------- final head: 64 n-tiles, 8 per wave
  {
    short8v A0 = ldA(xbf, 128, 0), A1 = ldA(xbf, 128, 1),
            A2 = ldA(xbf, 128, 2), A3 = ldA(xbf, 128, 3);
    #pragma unroll
    for (int i = 0; i < 8; ++i) {
      int tile = w + 8 * i;
      const short8v* Bp = (const short8v*)(p.Wf + WT_OUT) + (size_t)(tile * 4) * 64 + lane;
      short8v b0 = Bp[0], b1 = Bp[64], b2 = Bp[128], b3 = Bp[192];
      f32x4 acc = {0.f, 0.f, 0.f, 0.f};
      acc = __builtin_amdgcn_mfma_f32_16x16x32_bf16(A0, b0, acc, 0, 0, 0);
      acc = __builtin_amdgcn_mfma_f32_16x16x32_bf16(A1, b1, acc, 0, 0, 0);
      acc = __builtin_amdgcn_mfma_f32_16x16x32_bf16(A2, b2, acc, 0, 0, 0);
      acc = __builtin_amdgcn_mfma_f32_16x16x32_bf16(A3, b3, acc, 0, 0, 0);
      if (lane < 32) {
        int col = tile * 16 + (lane & 15);
        float bv = p.bout[col];
        int rbase = (lane >> 4) * 4;
        #pragma unroll
        for (int j = 0; j < 4; ++j)
          p.out[(size_t)(batch * 128 + s0 + rbase + j) * 1024 + col] = acc[j] + bv;
      }
    }
  }
}

extern "C" void kernel_launch(void* const* d_in, const int* in_sizes, int n_in,
                              void* d_out, int out_size, void* d_ws, size_t ws_size,
                              hipStream_t stream)
{
  Params p;
  p.tok  = (const int*)d_in[0];
  p.emb  = (const float*)d_in[1];
  p.pos  = (const float*)d_in[2];
  p.Wq   = (const float*)d_in[3];  p.bq  = (const float*)d_in[4];
  p.Wk   = (const float*)d_in[5];  p.bk  = (const float*)d_in[6];
  p.Wv   = (const float*)d_in[7];  p.bv  = (const float*)d_in[8];
  p.Wo   = (const float*)d_in[9];  p.bo  = (const float*)d_in[10];
  p.W1   = (const float*)d_in[11]; p.b1  = (const float*)d_in[12];
  p.W2   = (const float*)d_in[13]; p.b2  = (const float*)d_in[14];
  p.g1   = (const float*)d_in[15]; p.be1 = (const float*)d_in[16];
  p.g2   = (const float*)d_in[17]; p.be2 = (const float*)d_in[18];
  p.Wout = (const float*)d_in[19]; p.bout = (const float*)d_in[20];

  p.Wf  = (ushort*)d_ws;                         // 524288 bf16 = 1 MB, tiled frags
  p.kv  = (float*)((ushort*)d_ws + 524288);      // 131072 floats: [l][K/V][b][s][d]
  p.ctr = (unsigned*)(p.kv + 131072);            // flag counters (init-gated)
  p.out = (float*)d_out;

  k_model<<<dim3(NBLK), dim3(TPB), 0, stream>>>(p);
}

// Round 10
// 147.814 us; speedup vs baseline: 2.7733x; 1.0197x over previous
//
#include <hip/hip_runtime.h>

#define NBLK 32
#define TPB 512

typedef __attribute__((ext_vector_type(8))) short short8v;
typedef __attribute__((ext_vector_type(4))) float f32x4;
typedef unsigned short ushort;

// Wf (bf16/ushort units), each matrix pre-tiled in MFMA B-frag order:
// idx = (((l*NT + nt)*KT + kt)*64 + lane)*8 + j ;  elem = W[n][k],
// n = nt*16 + (lane&15), k = kt*32 + (lane>>4)*8 + j
#define WT_Q   0
#define WT_K   32768
#define WT_V   65536
#define WT_O   98304
#define WT_1   131072
#define WT_2   262144
#define WT_OUT 393216

#define INIT_MAGIC 0xC0FFEE01u

// padded LDS strides (ushorts): 136*2B = 272B = 68 dw, 68%32=4 -> 2-way (free)
#define XS_STR 136
#define F1_STR 520

struct Params {
  const int* tok; const float* emb; const float* pos;
  const float* Wq; const float* bq; const float* Wk; const float* bk;
  const float* Wv; const float* bv; const float* Wo; const float* bo;
  const float* W1; const float* b1; const float* W2; const float* b2;
  const float* g1; const float* be1; const float* g2; const float* be2;
  const float* Wout; const float* bout;
  ushort* Wf; float* kv; unsigned* ctr; float* out;
};

// f(v) = rint(m*8)*2^(2e-3): <=4-bit mantissa -> exact in bf16.
__device__ __forceinline__ float lmul_tf(float v) {
  int e; float m = frexpf(v, &e);
  return ldexpf(rintf(m * 8.0f), 2 * e - 3);
}
__device__ __forceinline__ ushort bf16t(float v) {
  unsigned u; __builtin_memcpy(&u, &v, 4); return (ushort)(u >> 16);
}
__device__ __forceinline__ void store_f32_agent(float* dst, float v) {
  unsigned u; __builtin_memcpy(&u, &v, 4);
  __hip_atomic_store((unsigned*)dst, u, __ATOMIC_RELAXED, __HIP_MEMORY_SCOPE_AGENT);
}
__device__ __forceinline__ void store_u64_agent(unsigned long long* dst, unsigned long long v) {
  __hip_atomic_store(dst, v, __ATOMIC_RELAXED, __HIP_MEMORY_SCOPE_AGENT);
}

__global__ __launch_bounds__(512, 1) void k_model(Params p) {
  __shared__ __align__(16) float xs [8][132];      // raw x rows
  __shared__ __align__(16) float qs [8][132];      // Q rows fp32
  __shared__ __align__(16) float tmp[8][132];      // pre-LN
  __shared__ __align__(16) float ps [8][4][129];   // probs
  __shared__ __align__(16) float kscr[32][132];    // K/V staging
  __shared__ __align__(16) ushort xbf [16 * XS_STR]; // bf16 f(x), rows 8-15 zero
  __shared__ __align__(16) ushort atbf[16 * XS_STR]; // bf16 f(attn), rows 8-15 zero
  __shared__ __align__(16) ushort f1bf[16 * F1_STR]; // bf16 f(relu(ff1)), rows 8-15 zero

  const int bid = blockIdx.x, t = threadIdx.x;
  const int batch = bid >> 4, s0 = (bid & 15) * 8;
  const int lane = t & 63, w = t >> 6;

  // ---------------- phase 0: transform weights -> bf16 tiled frags (grid-split); embed
  {
    int tid = bid * TPB + t;
    #pragma unroll
    for (int it = 0; it < 4; ++it) {
      int chunk = tid + it * 16384;            // 65536 chunks of 8 elems
      int e = chunk * 8;
      const float* src; int dstbase, K, rem, pls, ktb;
      if (e < 131072) {
        int m = e >> 15;
        src = (m == 0 ? p.Wq : m == 1 ? p.Wk : m == 2 ? p.Wv : p.Wo);
        dstbase = m * 32768; K = 128; rem = e & 32767; pls = 14; ktb = 2;
      } else if (e < 262144) {
        src = p.W1; dstbase = WT_1; K = 128; rem = e - 131072; pls = 16; ktb = 2;
      } else if (e < 393216) {
        src = p.W2; dstbase = WT_2; K = 512; rem = e - 262144; pls = 16; ktb = 4;
      } else {
        src = p.Wout; dstbase = WT_OUT; K = 128; rem = e - 393216; pls = 17; ktb = 2;
      }
      int l = rem >> pls, r2 = rem & ((1 << pls) - 1);
      int fragl = r2 >> 3;
      int lane_id = fragl & 63, ftile = fragl >> 6;
      int kt = ftile & ((1 << ktb) - 1), nt = ftile >> ktb;
      int n = nt * 16 + (lane_id & 15);
      int k0 = kt * 32 + (lane_id >> 4) * 8;
      const float* sp = src + ((size_t)l << pls) + (size_t)n * K + k0;
      float4 v0 = *(const float4*)sp, v1 = *(const float4*)(sp + 4);
      unsigned u0 = bf16t(lmul_tf(v0.x)) | ((unsigned)bf16t(lmul_tf(v0.y)) << 16);
      unsigned u1 = bf16t(lmul_tf(v0.z)) | ((unsigned)bf16t(lmul_tf(v0.w)) << 16);
      unsigned u2 = bf16t(lmul_tf(v1.x)) | ((unsigned)bf16t(lmul_tf(v1.y)) << 16);
      unsigned u3 = bf16t(lmul_tf(v1.z)) | ((unsigned)bf16t(lmul_tf(v1.w)) << 16);
      unsigned long long* dp = (unsigned long long*)(p.Wf + dstbase + rem);
      store_u64_agent(dp,     (unsigned long long)u0 | ((unsigned long long)u1 << 32));
      store_u64_agent(dp + 1, (unsigned long long)u2 | ((unsigned long long)u3 << 32));
    }
    // zero padded rows 8-15 of the bf16 tiles (disjoint from rows 0-7 fills)
    for (int i = t; i < 544; i += TPB) {
      ((unsigned*)xbf)[544 + i] = 0;
      ((unsigned*)atbf)[544 + i] = 0;
    }
    for (int i = t; i < 2080; i += TPB) ((unsigned*)f1bf)[2080 + i] = 0;
    for (int i = t; i < 8 * 128; i += TPB) {
      int rr = i >> 7, d = i & 127;
      float val = p.emb[p.tok[batch * 128 + s0 + rr] * 128 + d] + p.pos[(s0 + rr) * 128 + d];
      xs[rr][d] = val; xbf[rr * XS_STR + d] = bf16t(lmul_tf(val));
    }
  }
  // ---------------- weights-ready barrier (fence-free)
  {
    if (bid == 0 && t == 0) {
      #pragma unroll
      for (int i = 0; i < 5; ++i)
        __hip_atomic_store(p.ctr + 64 * i, 0u, __ATOMIC_RELAXED, __HIP_MEMORY_SCOPE_AGENT);
      asm volatile("s_waitcnt vmcnt(0)" ::: "memory");
      __hip_atomic_store(p.ctr + 320, INIT_MAGIC, __ATOMIC_RELAXED, __HIP_MEMORY_SCOPE_AGENT);
    }
    asm volatile("s_waitcnt vmcnt(0)" ::: "memory");
    __syncthreads();
    if (t == 0) {
      while (__hip_atomic_load(p.ctr + 320, __ATOMIC_RELAXED, __HIP_MEMORY_SCOPE_AGENT) != INIT_MAGIC)
        __builtin_amdgcn_s_sleep(1);
      __hip_atomic_fetch_add(p.ctr, 1u, __ATOMIC_RELAXED, __HIP_MEMORY_SCOPE_AGENT);
      while (__hip_atomic_load(p.ctr, __ATOMIC_RELAXED, __HIP_MEMORY_SCOPE_AGENT) < 32u)
        __builtin_amdgcn_s_sleep(1);
    }
    __syncthreads();
    asm volatile("" ::: "memory");
  }

  auto kv_barrier = [&](int l) {
    unsigned* c = p.ctr + 64 * (1 + l * 2 + batch);
    asm volatile("s_waitcnt vmcnt(0)" ::: "memory");
    __syncthreads();
    if (t == 0) {
      __hip_atomic_fetch_add(c, 1u, __ATOMIC_RELAXED, __HIP_MEMORY_SCOPE_AGENT);
      while (__hip_atomic_load(c, __ATOMIC_RELAXED, __HIP_MEMORY_SCOPE_AGENT) < 16u)
        __builtin_amdgcn_s_sleep(1);
    }
    __syncthreads();
    asm volatile("" ::: "memory");
  };

  // A-frag: m = lane&15, k = kt*32 + (lane>>4)*8 + j   (padded stride)
  auto ldA = [&](const ushort* Ab, int stride, int kt) -> short8v {
    return *(const short8v*)(Ab + (lane & 15) * stride + kt * 32 + ((lane >> 4) & 3) * 8);
  };

  // ---------------- QKV via MFMA: 24 n-tiles, 3 per wave
  auto qkv = [&](int l) {
    short8v A0 = ldA(xbf, XS_STR, 0), A1 = ldA(xbf, XS_STR, 1),
            A2 = ldA(xbf, XS_STR, 2), A3 = ldA(xbf, XS_STR, 3);
    #pragma unroll
    for (int i = 0; i < 3; ++i) {
      int tile = w + 8 * i;
      int proj = tile >> 3, nt = tile & 7;
      const short8v* Bp = (const short8v*)(p.Wf + (proj == 0 ? WT_Q : proj == 1 ? WT_K : WT_V))
                          + (size_t)((l * 8 + nt) * 4) * 64 + lane;
      short8v b0 = Bp[0], b1 = Bp[64], b2 = Bp[128], b3 = Bp[192];
      f32x4 acc = {0.f, 0.f, 0.f, 0.f};
      acc = __builtin_amdgcn_mfma_f32_16x16x32_bf16(A0, b0, acc, 0, 0, 0);
      acc = __builtin_amdgcn_mfma_f32_16x16x32_bf16(A1, b1, acc, 0, 0, 0);
      acc = __builtin_amdgcn_mfma_f32_16x16x32_bf16(A2, b2, acc, 0, 0, 0);
      acc = __builtin_amdgcn_mfma_f32_16x16x32_bf16(A3, b3, acc, 0, 0, 0);
      if (lane < 32) {
        int col = tile * 16 + (lane & 15);
        int rbase = (lane >> 4) * 4;
        if (proj == 0) {
          float bv = p.bq[l * 128 + col];
          #pragma unroll
          for (int j = 0; j < 4; ++j) qs[rbase + j][col] = acc[j] + bv;
        } else {
          int d = col & 127;
          float bv = (proj == 1 ? p.bk : p.bv)[l * 128 + d];
          float* dst = p.kv + (size_t)((l * 2 + (proj - 1)) * 2 + batch) * 16384 + d;
          #pragma unroll
          for (int j = 0; j < 4; ++j)
            store_f32_agent(dst + (size_t)(s0 + rbase + j) * 128, acc[j] + bv);
        }
      }
    }
    __syncthreads();
  };

  // ---------------- attention: fp32 (K/V via LDS chunks; PV float4, 256 threads)
  auto attn = [&](int l) {
    const float* Kb = p.kv + (size_t)((l * 2 + 0) * 2 + batch) * 16384;
    const float* Vb = p.kv + (size_t)((l * 2 + 1) * 2 + batch) * 16384;
    int rq = t >> 6, h = (t >> 4) & 3, kc = t & 15;
    float4 qv[8];
    #pragma unroll
    for (int d4 = 0; d4 < 8; ++d4) qv[d4] = *(const float4*)&qs[rq][h * 32 + d4 * 4];
    float sc[8];
    for (int chunk = 0; chunk < 4; ++chunk) {
      #pragma unroll
      for (int u = 0; u < 2; ++u) {
        int idx = t + u * 512, row = idx >> 5, col4 = idx & 31;
        *(float4*)&kscr[row][col4 * 4] =
            *(const float4*)(Kb + (chunk * 32 + row) * 128 + col4 * 4);
      }
      __syncthreads();
      #pragma unroll
      for (int m2 = 0; m2 < 2; ++m2) {
        int sl = kc + 16 * m2;
        float a = 0.f;
        #pragma unroll
        for (int d4 = 0; d4 < 8; ++d4) {
          float4 k4 = *(const float4*)&kscr[sl][h * 32 + d4 * 4];
          a += qv[d4].x * k4.x + qv[d4].y * k4.y + qv[d4].z * k4.z + qv[d4].w * k4.w;
        }
        sc[chunk * 2 + m2] = a * 0.17677669529663687f;
      }
      __syncthreads();
    }
    float mx = -1e30f;
    #pragma unroll
    for (int m = 0; m < 8; ++m) mx = fmaxf(mx, sc[m]);
    #pragma unroll
    for (int off = 1; off < 16; off <<= 1) mx = fmaxf(mx, __shfl_xor(mx, off));
    float sum = 0.f;
    #pragma unroll
    for (int m = 0; m < 8; ++m) { sc[m] = expf(sc[m] - mx); sum += sc[m]; }
    #pragma unroll
    for (int off = 1; off < 16; off <<= 1) sum += __shfl_xor(sum, off);
    float inv = 1.f / sum;
    #pragma unroll
    for (int m = 0; m < 8; ++m) ps[rq][h][kc + 16 * m] = sc[m] * inv;
    __syncthreads();
    // PV: 256 active threads, thread = (row r2, d-quad dq)
    int r2 = t & 7, dq = (t >> 3) & 31, hh = dq >> 3;
    f32x4 av = {0.f, 0.f, 0.f, 0.f};
    for (int ch = 0; ch < 4; ++ch) {
      #pragma unroll
      for (int u = 0; u < 2; ++u) {
        int idx = t + u * 512, row = idx >> 5, col4 = idx & 31;
        *(float4*)&kscr[row][col4 * 4] =
            *(const float4*)(Vb + (ch * 32 + row) * 128 + col4 * 4);
      }
      __syncthreads();
      if (t < 256) {
        #pragma unroll
        for (int ss = 0; ss < 32; ++ss) {
          float pp = ps[r2][hh][ch * 32 + ss];
          float4 vv = *(const float4*)&kscr[ss][dq * 4];
          av.x += pp * vv.x; av.y += pp * vv.y;
          av.z += pp * vv.z; av.w += pp * vv.w;
        }
      }
      __syncthreads();
    }
    if (t < 256) {
      int d0 = dq * 4;
      atbf[r2 * XS_STR + d0 + 0] = bf16t(lmul_tf(av.x));
      atbf[r2 * XS_STR + d0 + 1] = bf16t(lmul_tf(av.y));
      atbf[r2 * XS_STR + d0 + 2] = bf16t(lmul_tf(av.z));
      atbf[r2 * XS_STR + d0 + 3] = bf16t(lmul_tf(av.w));
    }
    __syncthreads();
  };

  auto lnorm = [&](const float* g, const float* be, int l) {
    int rw = t >> 6, li = t & 63;
    float v0 = tmp[rw][li], v1 = tmp[rw][li + 64];
    float s = v0 + v1, s2 = v0 * v0 + v1 * v1;
    #pragma unroll
    for (int off = 1; off < 64; off <<= 1) { s += __shfl_xor(s, off); s2 += __shfl_xor(s2, off); }
    float mu = s * (1.f / 128.f);
    float var = s2 * (1.f / 128.f) - mu * mu;
    float rr2 = rsqrtf(var + 1e-5f);
    float n0 = (v0 - mu) * rr2 * g[l * 128 + li]      + be[l * 128 + li];
    float n1 = (v1 - mu) * rr2 * g[l * 128 + li + 64] + be[l * 128 + li + 64];
    xs[rw][li] = n0;       xs[rw][li + 64] = n1;
    xbf[rw * XS_STR + li]      = bf16t(lmul_tf(n0));
    xbf[rw * XS_STR + li + 64] = bf16t(lmul_tf(n1));
  };

  // ---------------- O-proj + LN: 8 n-tiles, 1 per wave
  auto oproj_ln = [&](int l) {
    short8v A0 = ldA(atbf, XS_STR, 0), A1 = ldA(atbf, XS_STR, 1),
            A2 = ldA(atbf, XS_STR, 2), A3 = ldA(atbf, XS_STR, 3);
    const short8v* Bp = (const short8v*)(p.Wf + WT_O) + (size_t)((l * 8 + w) * 4) * 64 + lane;
    short8v b0 = Bp[0], b1 = Bp[64], b2 = Bp[128], b3 = Bp[192];
    f32x4 acc = {0.f, 0.f, 0.f, 0.f};
    acc = __builtin_amdgcn_mfma_f32_16x16x32_bf16(A0, b0, acc, 0, 0, 0);
    acc = __builtin_amdgcn_mfma_f32_16x16x32_bf16(A1, b1, acc, 0, 0, 0);
    acc = __builtin_amdgcn_mfma_f32_16x16x32_bf16(A2, b2, acc, 0, 0, 0);
    acc = __builtin_amdgcn_mfma_f32_16x16x32_bf16(A3, b3, acc, 0, 0, 0);
    if (lane < 32) {
      int col = w * 16 + (lane & 15);
      float bv = p.bo[l * 128 + col];
      int rbase = (lane >> 4) * 4;
      #pragma unroll
      for (int j = 0; j < 4; ++j)
        tmp[rbase + j][col] = acc[j] + bv + xs[rbase + j][col];
    }
    __syncthreads();
    lnorm(p.g1, p.be1, l);
    __syncthreads();
  };

  // ---------------- FFN
  auto ffn = [&](int l) {
    { // FF1: 32 n-tiles, 4 per wave
      short8v A0 = ldA(xbf, XS_STR, 0), A1 = ldA(xbf, XS_STR, 1),
              A2 = ldA(xbf, XS_STR, 2), A3 = ldA(xbf, XS_STR, 3);
      #pragma unroll
      for (int i = 0; i < 4; ++i) {
        int tile = w + 8 * i;
        const short8v* Bp = (const short8v*)(p.Wf + WT_1) + (size_t)((l * 32 + tile) * 4) * 64 + lane;
        short8v b0 = Bp[0], b1 = Bp[64], b2 = Bp[128], b3 = Bp[192];
        f32x4 acc = {0.f, 0.f, 0.f, 0.f};
        acc = __builtin_amdgcn_mfma_f32_16x16x32_bf16(A0, b0, acc, 0, 0, 0);
        acc = __builtin_amdgcn_mfma_f32_16x16x32_bf16(A1, b1, acc, 0, 0, 0);
        acc = __builtin_amdgcn_mfma_f32_16x16x32_bf16(A2, b2, acc, 0, 0, 0);
        acc = __builtin_amdgcn_mfma_f32_16x16x32_bf16(A3, b3, acc, 0, 0, 0);
        if (lane < 32) {
          int col = tile * 16 + (lane & 15);
          float bv = p.b1[l * 512 + col];
          int rbase = (lane >> 4) * 4;
          #pragma unroll
          for (int j = 0; j < 4; ++j)
            f1bf[(rbase + j) * F1_STR + col] = bf16t(lmul_tf(fmaxf(acc[j] + bv, 0.f)));
        }
      }
    }
    __syncthreads();
    { // FF2: K=512 -> 16 k-tiles; 8 n-tiles, 1 per wave
      const short8v* Bp = (const short8v*)(p.Wf + WT_2) + (size_t)((l * 8 + w) * 16) * 64 + lane;
      short8v Bf[16];
      #pragma unroll
      for (int kt = 0; kt < 16; ++kt) Bf[kt] = Bp[(size_t)kt * 64];
      f32x4 acc = {0.f, 0.f, 0.f, 0.f};
      #pragma unroll
      for (int kt = 0; kt < 16; ++kt) {
        short8v a = *(const short8v*)(f1bf + (lane & 15) * F1_STR + kt * 32 + ((lane >> 4) & 3) * 8);
        acc = __builtin_amdgcn_mfma_f32_16x16x32_bf16(a, Bf[kt], acc, 0, 0, 0);
      }
      if (lane < 32) {
        int col = w * 16 + (lane & 15);
        float bv = p.b2[l * 128 + col];
        int rbase = (lane >> 4) * 4;
        #pragma unroll
        for (int j = 0; j < 4; ++j)
          tmp[rbase + j][col] = acc[j] + bv + xs[rbase + j][col];
      }
      __syncthreads();
      lnorm(p.g2, p.be2, l);
      __syncthreads();
    }
  };

  qkv(0);
  kv_barrier(0);
  attn(0);
  oproj_ln(0);
  ffn(0);
  qkv(1);
  kv_barrier(1);
  attn(1);
  oproj_ln(1);
  ffn(1);

  // ---------------- final head: 64 n-tiles, 8 per wave
  {
    short8v A0 = ldA(xbf, XS_STR, 0), A1 = ldA(xbf, XS_STR, 1),
            A2 = ldA(xbf, XS_STR, 2), A3 = ldA(xbf, XS_STR, 3);
    #pragma unroll
    for (int i = 0; i < 8; ++i) {
      int tile = w + 8 * i;
      const short8v* Bp = (const short8v*)(p.Wf + WT_OUT) + (size_t)(tile * 4) * 64 + lane;
      short8v b0 = Bp[0], b1 = Bp[64], b2 = Bp[128], b3 = Bp[192];
      f32x4 acc = {0.f, 0.f, 0.f, 0.f};
      acc = __builtin_amdgcn_mfma_f32_16x16x32_bf16(A0, b0, acc, 0, 0, 0);
      acc = __builtin_amdgcn_mfma_f32_16x16x32_bf16(A1, b1, acc, 0, 0, 0);
      acc = __builtin_amdgcn_mfma_f32_16x16x32_bf16(A2, b2, acc, 0, 0, 0);
      acc = __builtin_amdgcn_mfma_f32_16x16x32_bf16(A3, b3, acc, 0, 0, 0);
      if (lane < 32) {
        int col = tile * 16 + (lane & 15);
        float bv = p.bout[col];
        int rbase = (lane >> 4) * 4;
        #pragma unroll
        for (int j = 0; j < 4; ++j)
          p.out[(size_t)(batch * 128 + s0 + rbase + j) * 1024 + col] = acc[j] + bv;
      }
    }
  }
}

extern "C" void kernel_launch(void* const* d_in, const int* in_sizes, int n_in,
                              void* d_out, int out_size, void* d_ws, size_t ws_size,
                              hipStream_t stream)
{
  Params p;
  p.tok  = (const int*)d_in[0];
  p.emb  = (const float*)d_in[1];
  p.pos  = (const float*)d_in[2];
  p.Wq   = (const float*)d_in[3];  p.bq  = (const float*)d_in[4];
  p.Wk   = (const float*)d_in[5];  p.bk  = (const float*)d_in[6];
  p.Wv   = (const float*)d_in[7];  p.bv  = (const float*)d_in[8];
  p.Wo   = (const float*)d_in[9];  p.bo  = (const float*)d_in[10];
  p.W1   = (const float*)d_in[11]; p.b1  = (const float*)d_in[12];
  p.W2   = (const float*)d_in[13]; p.b2  = (const float*)d_in[14];
  p.g1   = (const float*)d_in[15]; p.be1 = (const float*)d_in[16];
  p.g2   = (const float*)d_in[17]; p.be2 = (const float*)d_in[18];
  p.Wout = (const float*)d_in[19]; p.bout = (const float*)d_in[20];

  p.Wf  = (ushort*)d_ws;                         // 524288 bf16 = 1 MB, tiled frags
  p.kv  = (float*)((ushort*)d_ws + 524288);      // 131072 floats: [l][K/V][b][s][d]
  p.ctr = (unsigned*)(p.kv + 131072);            // flag counters (init-gated)
  p.out = (float*)d_out;

  k_model<<<dim3(NBLK), dim3(TPB), 0, stream>>>(p);
}